// Round 3
// baseline (19454.480 us; speedup 1.0000x reference)
//
#include <hip/hip_runtime.h>
#include <stdint.h>

typedef uint16_t u16;
typedef unsigned long long u64;
typedef __attribute__((ext_vector_type(8))) short short8;   // 8 x bf16 bits (4 VGPRs)
typedef __attribute__((ext_vector_type(4))) float f32x4;

#define SCOPE __HIP_MEMORY_SCOPE_AGENT

static __device__ __forceinline__ float bf2f(u16 b) {
  union { uint32_t u; float f; } x; x.u = ((uint32_t)b) << 16; return x.f;
}
static __device__ __forceinline__ u16 f2bf(float f) {
  union { float f; uint32_t u; } x; x.f = f;
  uint32_t u = x.u;
  u += 0x7fffu + ((u >> 16) & 1u);   // RTNE
  return (u16)(u >> 16);
}
static __device__ __forceinline__ float sigm(float x) {
  x = fminf(30.f, fmaxf(-30.f, x));
  return 1.f / (1.f + __expf(-x));
}
static __device__ __forceinline__ float tanhf_(float x) {
  x = fminf(15.f, fmaxf(-15.f, x));
  float e = __expf(2.f * x);
  return (e - 1.f) / (e + 1.f);
}

// Persistent pipelined GRU. One WG per (layer L in 0..63, chunk g in 0..3 of 32 batch rows).
// t = 0..511: enc steps 0..255 (enc weights), dec 256..511 (dec weights), h carried.
// Layer-63 blocks also apply the output projection (out = h @ Wo^T + bo) per step,
// writing d_out directly — no intermediate y buffer, no second GEMM kernel.
// Cross-layer handoff: 4KB register-dump records via agent-scope atomics in a ring;
// per-WAVE release flags, consumer waves acquire-spin on all 4 (lane&3).
// Inputs may be bf16 OR fp32 (harness-dependent): detected at runtime from enc_bih
// bit patterns (even u16s of a bf16 array have sane exponents; low halves of fp32
// words do not). All input loads / output stores branch on the detected mode.
// MFMA 16x16x32 bf16 layouts (m89-verified):
//   A: lane holds A[m=lane&15][k=(lane>>4)*8 + j]
//   B: lane holds B[k=(lane>>4)*8 + j][n=lane&15]  (8 contiguous k of row n of W, W=(N,K) row-major)
//   C/D: reg p -> (row=(lane>>4)*4+p, col=lane&15)
__global__ __launch_bounds__(256, 1) void gru_pipeline(
    const void* ctx_,
    const void* eWih0_, const void* eWih_, const void* eWhh_,
    const void* ebih_,  const void* ebhh_,
    const void* dWih0_, const void* dWih_, const void* dWhh_,
    const void* dbih_,  const void* dbhh_,
    const void* Wo_,    const void* bo_,   void* out_,
    int* __restrict__ pflag, int* __restrict__ cflag,
    u64* __restrict__ xbuf, int RING)
{
  const int tid  = threadIdx.x;
  const int lane = tid & 63;
  const int wid  = tid >> 6;
  const int rt   = wid >> 1;      // row-tile (16 batch rows each)
  const int cs   = wid & 1;       // gate-col half
  const int lo   = lane & 15;
  const int hi   = lane >> 4;
  const int blk  = blockIdx.x;
  const int L    = blk >> 2;
  const int g    = blk & 3;
  const int KIN  = (L == 0) ? 128 : 64;
  const int NKC  = KIN >> 5;

  __shared__ __align__(16) u16 hb[2][32 * 72];
  __shared__ __align__(16) u16 xst[32 * 72];
  __shared__ int s_cnt;
  if (tid == 0) s_cnt = 0;
  for (int i = tid; i < 2 * 32 * 72; i += 256) (&hb[0][0])[i] = 0;
  for (int i = tid; i < 32 * 72; i += 256) xst[i] = 0;
  __syncthreads();
  {  // dtype probe: even u16s of enc_bih (12288 elems either way)
    u16 v = ((const u16*)ebih_)[2 * tid];
    int e = (v >> 7) & 0xFF;
    if (e >= 100 && e <= 126) atomicAdd(&s_cnt, 1);
  }
  __syncthreads();
  const bool bf = (s_cnt >= 128);   // true: tensors are bf16; false: fp32

  auto ld8 = [&](const void* p, int idx) -> short8 {   // 8 elems -> bf16 frag
    if (bf) return *(const short8*)((const u16*)p + idx);
    const float* f = (const float*)p + idx;
    short8 r;
#pragma unroll
    for (int j = 0; j < 8; ++j) r[j] = (short)f2bf(f[j]);
    return r;
  };
  auto ld1 = [&](const void* p, int idx) -> float {
    return bf ? bf2f(((const u16*)p)[idx]) : ((const float*)p)[idx];
  };

  int T[6];
  T[0] = 2*cs; T[1] = 2*cs+1; T[2] = 4+2*cs; T[3] = 5+2*cs; T[4] = 8+2*cs; T[5] = 9+2*cs;

  short8 zf8 = {0,0,0,0,0,0,0,0};
  short8 wh[6][2];
  short8 wi[6][4];
  short8 wo[2][2];                 // layer-63 only: Wo B-frags
  float  bov[2] = {0.f, 0.f};
  float brz[4], bin2[2], bhn2[2];
#pragma unroll
  for (int a = 0; a < 6; ++a) { wh[a][0]=zf8; wh[a][1]=zf8;
#pragma unroll
    for (int b = 0; b < 4; ++b) wi[a][b]=zf8; }
  wo[0][0]=wo[0][1]=wo[1][0]=wo[1][1]=zf8;

  auto load_phase = [&](int ph) {
    const void* WH = ph ? dWhh_ : eWhh_;
    const void* WI = (L == 0) ? (ph ? dWih0_ : eWih0_) : (ph ? dWih_ : eWih_);
    const int  wbase = L * 192 * 64;
    const int  ibase = (L == 0) ? 0 : (L - 1) * 192 * 64;
    const void* bi = ph ? dbih_ : ebih_;
    const void* bh = ph ? dbhh_ : ebhh_;
#pragma unroll
    for (int ti = 0; ti < 6; ++ti) {
#pragma unroll
      for (int kc = 0; kc < 2; ++kc)
        wh[ti][kc] = ld8(WH, wbase + (T[ti]*16 + lo)*64 + kc*32 + hi*8);
#pragma unroll
      for (int kc = 0; kc < 4; ++kc)
        if (kc < NKC)
          wi[ti][kc] = ld8(WI, ibase + (T[ti]*16 + lo)*KIN + kc*32 + hi*8);
    }
#pragma unroll
    for (int q = 0; q < 4; ++q)
      brz[q] = ld1(bi, L*192 + T[q]*16 + lo) + ld1(bh, L*192 + T[q]*16 + lo);
#pragma unroll
    for (int q = 0; q < 2; ++q) {
      bin2[q] = ld1(bi, L*192 + T[4+q]*16 + lo);
      bhn2[q] = ld1(bh, L*192 + T[4+q]*16 + lo);
    }
  };
  load_phase(0);
  if (L == 63) {
#pragma unroll
    for (int ct = 0; ct < 2; ++ct) {
      int n = 32*wid + 16*ct + lo;
#pragma unroll
      for (int kc = 0; kc < 2; ++kc)
        wo[ct][kc] = ld8(Wo_, n*64 + kc*32 + hi*8);
      bov[ct] = ld1(bo_, n);
    }
  }

  float hprev[2][4];
#pragma unroll
  for (int q = 0; q < 2; ++q)
#pragma unroll
    for (int p = 0; p < 4; ++p) hprev[q][p] = 0.f;

  short8 xf[4] = {zf8, zf8, zf8, zf8};
  const int brow = 32*g + rt*16 + lo;
  if (L == 0) {
#pragma unroll
    for (int kc = 0; kc < 4; ++kc)
      xf[kc] = ld8(ctx_, (brow * 256 + 0) * 128 + kc*32 + hi*8);
  }

  const int eIn  = (L > 0 ? L - 1 : 0) * 4 + g;   // deref'd only when L>0
  const int eOut = (L < 63 ? L : 62) * 4 + g;     // deref'd only when L<63
  const u64* recin  = xbuf + (size_t)eIn  * RING * 512;
  u64*       recout = xbuf + (size_t)eOut * RING * 512;
  int* fin   = pflag + eIn * 4;
  int* fout  = pflag + eOut * 4;
  int* cself = cflag + (L * 4 + g) * 4;
  int* cnext = cflag + ((L < 63 ? L + 1 : 63) * 4 + g) * 4;

  int budget = 1 << 21;   // anti-hang: waits degrade to no-ops if exhausted

  __syncthreads();

  for (int t = 0; t < 512; ++t) {
    if (t == 256) load_phase(1);

    // ring backpressure: slot t%RING free once all 4 consumer waves consumed t-RING
    if (L < 63 && t >= RING) {
      while (__hip_atomic_load(cnext + (lane & 3), __ATOMIC_ACQUIRE, SCOPE) < t + 1 - RING
             && budget > 0) {
        --budget; __builtin_amdgcn_s_sleep(2);
      }
    }
    // wait for x_t: all 4 producer waves published step t
    if (L > 0) {
      while (__hip_atomic_load(fin + (lane & 3), __ATOMIC_ACQUIRE, SCOPE) < t + 1
             && budget > 0) {
        --budget; __builtin_amdgcn_s_sleep(2);
      }
    }
    __syncthreads();   // B1: hb(t-1) writes -> reads; xst reads(t-1) -> writes(t)

    // ---- stage x_t record -> LDS row-major (layers >= 1)
    if (L > 0) {
      const u64* rec = recin + (size_t)(t % RING) * 512 + tid * 2;
      u64 a = __hip_atomic_load(rec,     __ATOMIC_RELAXED, SCOPE);
      u64 b = __hip_atomic_load(rec + 1, __ATOMIC_RELAXED, SCOPE);
      const int row = (tid >> 7) * 16 + ((tid >> 4) & 3) * 4;
      const int col = ((tid >> 6) & 1) * 32 + (tid & 15);
#pragma unroll
      for (int p = 0; p < 4; ++p) {
        xst[(row + p) * 72 + col]      = (u16)(a >> (16 * p));
        xst[(row + p) * 72 + col + 16] = (u16)(b >> (16 * p));
      }
    }

    // ---- accumulators seeded with biases
    f32x4 acc_rz[4], acc_in[2], acc_hn[2];
#pragma unroll
    for (int q = 0; q < 4; ++q) { float v = brz[q];  f32x4 tv = {v, v, v, v}; acc_rz[q] = tv; }
#pragma unroll
    for (int q = 0; q < 2; ++q) { float v = bin2[q]; f32x4 tv = {v, v, v, v}; acc_in[q] = tv;
                                  float w = bhn2[q]; f32x4 tw = {w, w, w, w}; acc_hn[q] = tw; }

    // ---- gh = h_{t-1} @ Whh^T
    const u16* hsrc = hb[(t + 1) & 1];
#pragma unroll
    for (int kc = 0; kc < 2; ++kc) {
      short8 hA = *(const short8*)(hsrc + (rt*16 + lo)*72 + kc*32 + hi*8);
      acc_rz[0] = __builtin_amdgcn_mfma_f32_16x16x32_bf16(hA, wh[0][kc], acc_rz[0], 0, 0, 0);
      acc_rz[1] = __builtin_amdgcn_mfma_f32_16x16x32_bf16(hA, wh[1][kc], acc_rz[1], 0, 0, 0);
      acc_rz[2] = __builtin_amdgcn_mfma_f32_16x16x32_bf16(hA, wh[2][kc], acc_rz[2], 0, 0, 0);
      acc_rz[3] = __builtin_amdgcn_mfma_f32_16x16x32_bf16(hA, wh[3][kc], acc_rz[3], 0, 0, 0);
      acc_hn[0] = __builtin_amdgcn_mfma_f32_16x16x32_bf16(hA, wh[4][kc], acc_hn[0], 0, 0, 0);
      acc_hn[1] = __builtin_amdgcn_mfma_f32_16x16x32_bf16(hA, wh[5][kc], acc_hn[1], 0, 0, 0);
    }

    if (L > 0) {
      __syncthreads();   // B2: xst writes -> reads
#pragma unroll
      for (int kc = 0; kc < 2; ++kc)
        xf[kc] = *(const short8*)(xst + (rt*16 + lo)*72 + kc*32 + hi*8);
    }

    // ---- gi = x_t @ Wih^T  (dec_in[:,0] == 0 -> skip at t==256 for layer 0)
    if (!(L == 0 && t == 256)) {
#pragma unroll
      for (int kc = 0; kc < 4; ++kc) {
        if (kc < NKC) {
          acc_rz[0] = __builtin_amdgcn_mfma_f32_16x16x32_bf16(xf[kc], wi[0][kc], acc_rz[0], 0, 0, 0);
          acc_rz[1] = __builtin_amdgcn_mfma_f32_16x16x32_bf16(xf[kc], wi[1][kc], acc_rz[1], 0, 0, 0);
          acc_rz[2] = __builtin_amdgcn_mfma_f32_16x16x32_bf16(xf[kc], wi[2][kc], acc_rz[2], 0, 0, 0);
          acc_rz[3] = __builtin_amdgcn_mfma_f32_16x16x32_bf16(xf[kc], wi[3][kc], acc_rz[3], 0, 0, 0);
          acc_in[0] = __builtin_amdgcn_mfma_f32_16x16x32_bf16(xf[kc], wi[4][kc], acc_in[0], 0, 0, 0);
          acc_in[1] = __builtin_amdgcn_mfma_f32_16x16x32_bf16(xf[kc], wi[5][kc], acc_in[1], 0, 0, 0);
        }
      }
    }

    // ---- layer 0: prefetch x for t+1
    if (L == 0) {
      int tn = t + 1;
      int tt = (tn < 256) ? tn : ((tn == 256) ? 0 : tn - 257);
#pragma unroll
      for (int kc = 0; kc < 4; ++kc)
        xf[kc] = ld8(ctx_, (brow * 256 + tt) * 128 + kc*32 + hi*8);
    }

    // ---- gates (fp32; reg p -> batch row hi*4+p). |h|<=1 invariant; clamp = no-op guard
    u16 hbits[2][4];
#pragma unroll
    for (int q = 0; q < 2; ++q) {
#pragma unroll
      for (int p = 0; p < 4; ++p) {
        float r = sigm(acc_rz[q][p]);
        float z = sigm(acc_rz[2 + q][p]);
        float n = tanhf_(acc_in[q][p] + r * acc_hn[q][p]);
        float h = n + z * (hprev[q][p] - n);
        h = fminf(1.f, fmaxf(-1.f, h));
        hprev[q][p] = h;
        hbits[q][p] = f2bf(h);
      }
    }

    // ---- h_t -> LDS
    u16* hd = hb[t & 1];
#pragma unroll
    for (int q = 0; q < 2; ++q)
#pragma unroll
      for (int p = 0; p < 4; ++p)
        hd[(rt*16 + hi*4 + p) * 72 + cs*32 + q*16 + lo] = hbits[q][p];

    // ---- publish h_t: per-lane 16B record, then per-WAVE release flag
    if (L < 63) {
      u64 da = (u64)hbits[0][0] | ((u64)hbits[0][1] << 16) | ((u64)hbits[0][2] << 32) | ((u64)hbits[0][3] << 48);
      u64 db = (u64)hbits[1][0] | ((u64)hbits[1][1] << 16) | ((u64)hbits[1][2] << 32) | ((u64)hbits[1][3] << 48);
      u64* ro = recout + (size_t)(t % RING) * 512 + tid * 2;
      __hip_atomic_store(ro,     da, __ATOMIC_RELAXED, SCOPE);
      __hip_atomic_store(ro + 1, db, __ATOMIC_RELAXED, SCOPE);
      if (lane == 0)
        __hip_atomic_store(fout + wid, t + 1, __ATOMIC_RELEASE, SCOPE);
    }
    if (L > 0 && lane == 0)
      __hip_atomic_store(cself + wid, t + 1, __ATOMIC_RELEASE, SCOPE);

    // ---- layer 63, decoder steps: fused output projection out[:, t-256, :] from hb[t&1]
    if (L == 63 && t >= 256) {
      __syncthreads();   // hd writes (all waves) -> full-h reads
      const u16* hs = hb[t & 1];
      f32x4 pacc[2][2];
#pragma unroll
      for (int rtl = 0; rtl < 2; ++rtl)
#pragma unroll
        for (int ct = 0; ct < 2; ++ct) {
          float v = bov[ct]; f32x4 tv = {v, v, v, v}; pacc[rtl][ct] = tv;
        }
#pragma unroll
      for (int kc = 0; kc < 2; ++kc) {
        short8 hA0 = *(const short8*)(hs + (0*16 + lo)*72 + kc*32 + hi*8);
        short8 hA1 = *(const short8*)(hs + (1*16 + lo)*72 + kc*32 + hi*8);
        pacc[0][0] = __builtin_amdgcn_mfma_f32_16x16x32_bf16(hA0, wo[0][kc], pacc[0][0], 0, 0, 0);
        pacc[0][1] = __builtin_amdgcn_mfma_f32_16x16x32_bf16(hA0, wo[1][kc], pacc[0][1], 0, 0, 0);
        pacc[1][0] = __builtin_amdgcn_mfma_f32_16x16x32_bf16(hA1, wo[0][kc], pacc[1][0], 0, 0, 0);
        pacc[1][1] = __builtin_amdgcn_mfma_f32_16x16x32_bf16(hA1, wo[1][kc], pacc[1][1], 0, 0, 0);
      }
#pragma unroll
      for (int rtl = 0; rtl < 2; ++rtl)
#pragma unroll
        for (int ct = 0; ct < 2; ++ct) {
          int n = 32*wid + 16*ct + lo;
#pragma unroll
          for (int p = 0; p < 4; ++p) {
            int b = 32*g + rtl*16 + hi*4 + p;
            size_t idx = ((size_t)b * 256 + (t - 256)) * 128 + n;
            float v = fminf(64.f, fmaxf(-64.f, pacc[rtl][ct][p]));
            if (bf) ((u16*)out_)[idx] = f2bf(v);
            else    ((float*)out_)[idx] = v;
          }
        }
    }
  }
}

extern "C" void kernel_launch(void* const* d_in, const int* in_sizes, int n_in,
                              void* d_out, int out_size, void* d_ws, size_t ws_size,
                              hipStream_t stream)
{
  char* ws = (char*)d_ws;
  int* pflag = (int*)ws;                 // 4KB: per-wave producer flags
  int* cflag = (int*)(ws + 4096);        // 4KB: per-wave consumer flags
  u64* xbuf  = (u64*)(ws + 16384);       // handoff ring

  size_t avail = (ws_size > 16384) ? ws_size - 16384 : 0;
  size_t per_ring = (size_t)63 * 4 * 4096;   // one ring slot across all (l,g) edges
  int RING = 1;
  while (RING < 64 && (size_t)RING * 2 * per_ring <= avail) RING *= 2;

  hipMemsetAsync(ws, 0, 16384, stream);  // zero flags every launch
  gru_pipeline<<<256, 256, 0, stream>>>(
      d_in[0], d_in[1], d_in[2], d_in[3], d_in[4], d_in[5],
      d_in[6], d_in[7], d_in[8], d_in[9], d_in[10], d_in[11], d_in[12],
      d_out, pflag, cflag, xbuf, RING);
  (void)in_sizes; (void)n_in; (void)out_size;
}

// Round 4
// 13673.781 us; speedup vs baseline: 1.4228x; 1.4228x over previous
//
#include <hip/hip_runtime.h>
#include <stdint.h>

typedef uint16_t u16;
typedef unsigned long long u64;
typedef __attribute__((ext_vector_type(8))) short short8;   // 8 x bf16 bits (4 VGPRs)
typedef __attribute__((ext_vector_type(4))) float f32x4;

#define SCOPE __HIP_MEMORY_SCOPE_AGENT

static __device__ __forceinline__ float bf2f(u16 b) {
  union { uint32_t u; float f; } x; x.u = ((uint32_t)b) << 16; return x.f;
}
static __device__ __forceinline__ u16 f2bf(float f) {
  union { float f; uint32_t u; } x; x.f = f;
  uint32_t u = x.u;
  u += 0x7fffu + ((u >> 16) & 1u);   // RTNE
  return (u16)(u >> 16);
}
static __device__ __forceinline__ float sigm(float x) {
  x = fminf(30.f, fmaxf(-30.f, x));
  return 1.f / (1.f + __expf(-x));
}
static __device__ __forceinline__ float tanhf_(float x) {
  x = fminf(15.f, fmaxf(-15.f, x));
  float e = __expf(2.f * x);
  return (e - 1.f) / (e + 1.f);
}

// Persistent pipelined GRU. One WG per (layer L in 0..63, chunk g in 0..3 of 32 batch rows).
// t = 0..511: enc steps 0..255 (enc weights), dec 256..511 (dec weights), h carried.
// Layer-63 blocks also apply the output projection per step, writing d_out directly.
// Cross-layer handoff: 4KB register-dump records via agent-scope atomics in a ring;
// per-WAVE release flags.  R4 change: polling is WAVE-0-ONLY, LANES 0-3 ONLY
// (was: all 4 waves x 64 lanes -> ~50M coherence-point loads -> fabric congestion,
// 414MB FETCH, d_eff ~300us).  Waves 1-3 are gated by B1 instead.
// MFMA 16x16x32 bf16 layouts (m89-verified):
//   A: lane holds A[m=lane&15][k=(lane>>4)*8 + j]
//   B: lane holds B[k=(lane>>4)*8 + j][n=lane&15]  (8 contiguous k of row n of W, W=(N,K) row-major)
//   C/D: reg p -> (row=(lane>>4)*4+p, col=lane&15)
__global__ __launch_bounds__(256, 1) void gru_pipeline(
    const void* ctx_,
    const void* eWih0_, const void* eWih_, const void* eWhh_,
    const void* ebih_,  const void* ebhh_,
    const void* dWih0_, const void* dWih_, const void* dWhh_,
    const void* dbih_,  const void* dbhh_,
    const void* Wo_,    const void* bo_,   void* out_,
    int* __restrict__ pflag, int* __restrict__ cflag,
    u64* __restrict__ xbuf, int RING)
{
  const int tid  = threadIdx.x;
  const int lane = tid & 63;
  const int wid  = tid >> 6;
  const int rt   = wid >> 1;      // row-tile (16 batch rows each)
  const int cs   = wid & 1;       // gate-col half
  const int lo   = lane & 15;
  const int hi   = lane >> 4;
  const int blk  = blockIdx.x;
  const int L    = blk >> 2;
  const int g    = blk & 3;
  const int KIN  = (L == 0) ? 128 : 64;
  const int NKC  = KIN >> 5;

  __shared__ __align__(16) u16 hb[2][32 * 72];
  __shared__ __align__(16) u16 xst[32 * 72];
  __shared__ int s_cnt;
  if (tid == 0) s_cnt = 0;
  for (int i = tid; i < 2 * 32 * 72; i += 256) (&hb[0][0])[i] = 0;
  for (int i = tid; i < 32 * 72; i += 256) xst[i] = 0;
  __syncthreads();
  {  // dtype probe: even u16s of enc_bih (12288 elems either way)
    u16 v = ((const u16*)ebih_)[2 * tid];
    int e = (v >> 7) & 0xFF;
    if (e >= 100 && e <= 126) atomicAdd(&s_cnt, 1);
  }
  __syncthreads();
  const bool bf = (s_cnt >= 128);   // true: tensors are bf16; false: fp32

  auto ld8 = [&](const void* p, int idx) -> short8 {   // 8 elems -> bf16 frag
    if (bf) return *(const short8*)((const u16*)p + idx);
    const float* f = (const float*)p + idx;
    short8 r;
#pragma unroll
    for (int j = 0; j < 8; ++j) r[j] = (short)f2bf(f[j]);
    return r;
  };
  auto ld1 = [&](const void* p, int idx) -> float {
    return bf ? bf2f(((const u16*)p)[idx]) : ((const float*)p)[idx];
  };

  int T[6];
  T[0] = 2*cs; T[1] = 2*cs+1; T[2] = 4+2*cs; T[3] = 5+2*cs; T[4] = 8+2*cs; T[5] = 9+2*cs;

  short8 zf8 = {0,0,0,0,0,0,0,0};
  short8 wh[6][2];
  short8 wi[6][4];
  short8 wo[2][2];                 // layer-63 only: Wo B-frags
  float  bov[2] = {0.f, 0.f};
  float brz[4], bin2[2], bhn2[2];
#pragma unroll
  for (int a = 0; a < 6; ++a) { wh[a][0]=zf8; wh[a][1]=zf8;
#pragma unroll
    for (int b = 0; b < 4; ++b) wi[a][b]=zf8; }
  wo[0][0]=wo[0][1]=wo[1][0]=wo[1][1]=zf8;

  auto load_phase = [&](int ph) {
    const void* WH = ph ? dWhh_ : eWhh_;
    const void* WI = (L == 0) ? (ph ? dWih0_ : eWih0_) : (ph ? dWih_ : eWih_);
    const int  wbase = L * 192 * 64;
    const int  ibase = (L == 0) ? 0 : (L - 1) * 192 * 64;
    const void* bi = ph ? dbih_ : ebih_;
    const void* bh = ph ? dbhh_ : ebhh_;
#pragma unroll
    for (int ti = 0; ti < 6; ++ti) {
#pragma unroll
      for (int kc = 0; kc < 2; ++kc)
        wh[ti][kc] = ld8(WH, wbase + (T[ti]*16 + lo)*64 + kc*32 + hi*8);
#pragma unroll
      for (int kc = 0; kc < 4; ++kc)
        if (kc < NKC)
          wi[ti][kc] = ld8(WI, ibase + (T[ti]*16 + lo)*KIN + kc*32 + hi*8);
    }
#pragma unroll
    for (int q = 0; q < 4; ++q)
      brz[q] = ld1(bi, L*192 + T[q]*16 + lo) + ld1(bh, L*192 + T[q]*16 + lo);
#pragma unroll
    for (int q = 0; q < 2; ++q) {
      bin2[q] = ld1(bi, L*192 + T[4+q]*16 + lo);
      bhn2[q] = ld1(bh, L*192 + T[4+q]*16 + lo);
    }
  };
  load_phase(0);
  if (L == 63) {
#pragma unroll
    for (int ct = 0; ct < 2; ++ct) {
      int n = 32*wid + 16*ct + lo;
#pragma unroll
      for (int kc = 0; kc < 2; ++kc)
        wo[ct][kc] = ld8(Wo_, n*64 + kc*32 + hi*8);
      bov[ct] = ld1(bo_, n);
    }
  }

  float hprev[2][4];
#pragma unroll
  for (int q = 0; q < 2; ++q)
#pragma unroll
    for (int p = 0; p < 4; ++p) hprev[q][p] = 0.f;

  short8 xf[4] = {zf8, zf8, zf8, zf8};
  const int brow = 32*g + rt*16 + lo;
  if (L == 0) {
#pragma unroll
    for (int kc = 0; kc < 4; ++kc)
      xf[kc] = ld8(ctx_, (brow * 256 + 0) * 128 + kc*32 + hi*8);
  }

  const int eIn  = (L > 0 ? L - 1 : 0) * 4 + g;   // deref'd only when L>0
  const int eOut = (L < 63 ? L : 62) * 4 + g;     // deref'd only when L<63
  const u64* recin  = xbuf + (size_t)eIn  * RING * 512;
  u64*       recout = xbuf + (size_t)eOut * RING * 512;
  int* fin   = pflag + eIn * 4;
  int* fout  = pflag + eOut * 4;
  int* cself = cflag + (L * 4 + g) * 4;
  int* cnext = cflag + ((L < 63 ? L + 1 : 63) * 4 + g) * 4;

  int budget = 1 << 22;   // anti-hang: waits degrade to no-ops if exhausted

  __syncthreads();

  for (int t = 0; t < 512; ++t) {
    if (t == 256) load_phase(1);

    // ---- R4: wave 0 / lanes 0-3 do ALL polling; waves 1-3 are gated by B1.
    if (wid == 0) {
      // ring backpressure: slot t%RING free once all 4 consumer waves consumed t-RING
      if (L < 63 && t >= RING) {
        while (budget > 0) {
          int v = (lane < 4) ? __hip_atomic_load(cnext + lane, __ATOMIC_ACQUIRE, SCOPE)
                             : 0x7fffffff;
          if (__all(v >= t + 1 - RING)) break;
          --budget; __builtin_amdgcn_s_sleep(8);
        }
      }
      // wait for x_t: all 4 producer waves published step t
      if (L > 0) {
        while (budget > 0) {
          int v = (lane < 4) ? __hip_atomic_load(fin + lane, __ATOMIC_ACQUIRE, SCOPE)
                             : 0x7fffffff;
          if (__all(v >= t + 1)) break;
          --budget; __builtin_amdgcn_s_sleep(8);
        }
      }
    }
    __syncthreads();   // B1: polls passed; hb(t-1) writes -> reads; xst reuse

    // ---- stage x_t record -> LDS row-major (layers >= 1)
    if (L > 0) {
      const u64* rec = recin + (size_t)(t % RING) * 512 + tid * 2;
      u64 a = __hip_atomic_load(rec,     __ATOMIC_RELAXED, SCOPE);
      u64 b = __hip_atomic_load(rec + 1, __ATOMIC_RELAXED, SCOPE);
      const int row = (tid >> 7) * 16 + ((tid >> 4) & 3) * 4;
      const int col = ((tid >> 6) & 1) * 32 + (tid & 15);
#pragma unroll
      for (int p = 0; p < 4; ++p) {
        xst[(row + p) * 72 + col]      = (u16)(a >> (16 * p));
        xst[(row + p) * 72 + col + 16] = (u16)(b >> (16 * p));
      }
    }

    // ---- accumulators seeded with biases
    f32x4 acc_rz[4], acc_in[2], acc_hn[2];
#pragma unroll
    for (int q = 0; q < 4; ++q) { float v = brz[q];  f32x4 tv = {v, v, v, v}; acc_rz[q] = tv; }
#pragma unroll
    for (int q = 0; q < 2; ++q) { float v = bin2[q]; f32x4 tv = {v, v, v, v}; acc_in[q] = tv;
                                  float w = bhn2[q]; f32x4 tw = {w, w, w, w}; acc_hn[q] = tw; }

    // ---- gh = h_{t-1} @ Whh^T
    const u16* hsrc = hb[(t + 1) & 1];
#pragma unroll
    for (int kc = 0; kc < 2; ++kc) {
      short8 hA = *(const short8*)(hsrc + (rt*16 + lo)*72 + kc*32 + hi*8);
      acc_rz[0] = __builtin_amdgcn_mfma_f32_16x16x32_bf16(hA, wh[0][kc], acc_rz[0], 0, 0, 0);
      acc_rz[1] = __builtin_amdgcn_mfma_f32_16x16x32_bf16(hA, wh[1][kc], acc_rz[1], 0, 0, 0);
      acc_rz[2] = __builtin_amdgcn_mfma_f32_16x16x32_bf16(hA, wh[2][kc], acc_rz[2], 0, 0, 0);
      acc_rz[3] = __builtin_amdgcn_mfma_f32_16x16x32_bf16(hA, wh[3][kc], acc_rz[3], 0, 0, 0);
      acc_hn[0] = __builtin_amdgcn_mfma_f32_16x16x32_bf16(hA, wh[4][kc], acc_hn[0], 0, 0, 0);
      acc_hn[1] = __builtin_amdgcn_mfma_f32_16x16x32_bf16(hA, wh[5][kc], acc_hn[1], 0, 0, 0);
    }

    if (L > 0) {
      __syncthreads();   // B2: xst writes -> reads
#pragma unroll
      for (int kc = 0; kc < 2; ++kc)
        xf[kc] = *(const short8*)(xst + (rt*16 + lo)*72 + kc*32 + hi*8);
    }

    // ---- gi = x_t @ Wih^T  (dec_in[:,0] == 0 -> skip at t==256 for layer 0)
    if (!(L == 0 && t == 256)) {
#pragma unroll
      for (int kc = 0; kc < 4; ++kc) {
        if (kc < NKC) {
          acc_rz[0] = __builtin_amdgcn_mfma_f32_16x16x32_bf16(xf[kc], wi[0][kc], acc_rz[0], 0, 0, 0);
          acc_rz[1] = __builtin_amdgcn_mfma_f32_16x16x32_bf16(xf[kc], wi[1][kc], acc_rz[1], 0, 0, 0);
          acc_rz[2] = __builtin_amdgcn_mfma_f32_16x16x32_bf16(xf[kc], wi[2][kc], acc_rz[2], 0, 0, 0);
          acc_rz[3] = __builtin_amdgcn_mfma_f32_16x16x32_bf16(xf[kc], wi[3][kc], acc_rz[3], 0, 0, 0);
          acc_in[0] = __builtin_amdgcn_mfma_f32_16x16x32_bf16(xf[kc], wi[4][kc], acc_in[0], 0, 0, 0);
          acc_in[1] = __builtin_amdgcn_mfma_f32_16x16x32_bf16(xf[kc], wi[5][kc], acc_in[1], 0, 0, 0);
        }
      }
    }

    // ---- layer 0: prefetch x for t+1
    if (L == 0) {
      int tn = t + 1;
      int tt = (tn < 256) ? tn : ((tn == 256) ? 0 : tn - 257);
#pragma unroll
      for (int kc = 0; kc < 4; ++kc)
        xf[kc] = ld8(ctx_, (brow * 256 + tt) * 128 + kc*32 + hi*8);
    }

    // ---- gates (fp32; reg p -> batch row hi*4+p). |h|<=1 invariant; clamp = no-op guard
    u16 hbits[2][4];
#pragma unroll
    for (int q = 0; q < 2; ++q) {
#pragma unroll
      for (int p = 0; p < 4; ++p) {
        float r = sigm(acc_rz[q][p]);
        float z = sigm(acc_rz[2 + q][p]);
        float n = tanhf_(acc_in[q][p] + r * acc_hn[q][p]);
        float h = n + z * (hprev[q][p] - n);
        h = fminf(1.f, fmaxf(-1.f, h));
        hprev[q][p] = h;
        hbits[q][p] = f2bf(h);
      }
    }

    // ---- h_t -> LDS
    u16* hd = hb[t & 1];
#pragma unroll
    for (int q = 0; q < 2; ++q)
#pragma unroll
      for (int p = 0; p < 4; ++p)
        hd[(rt*16 + hi*4 + p) * 72 + cs*32 + q*16 + lo] = hbits[q][p];

    // ---- publish h_t: per-lane 16B record, then per-WAVE release flag
    if (L < 63) {
      u64 da = (u64)hbits[0][0] | ((u64)hbits[0][1] << 16) | ((u64)hbits[0][2] << 32) | ((u64)hbits[0][3] << 48);
      u64 db = (u64)hbits[1][0] | ((u64)hbits[1][1] << 16) | ((u64)hbits[1][2] << 32) | ((u64)hbits[1][3] << 48);
      u64* ro = recout + (size_t)(t % RING) * 512 + tid * 2;
      __hip_atomic_store(ro,     da, __ATOMIC_RELAXED, SCOPE);
      __hip_atomic_store(ro + 1, db, __ATOMIC_RELAXED, SCOPE);
      if (lane == 0)
        __hip_atomic_store(fout + wid, t + 1, __ATOMIC_RELEASE, SCOPE);
    }
    if (L > 0 && lane == 0)
      __hip_atomic_store(cself + wid, t + 1, __ATOMIC_RELEASE, SCOPE);

    // ---- layer 63, decoder steps: fused output projection out[:, t-256, :] from hb[t&1]
    if (L == 63 && t >= 256) {
      __syncthreads();   // hd writes (all waves) -> full-h reads
      const u16* hs = hb[t & 1];
      f32x4 pacc[2][2];
#pragma unroll
      for (int rtl = 0; rtl < 2; ++rtl)
#pragma unroll
        for (int ct = 0; ct < 2; ++ct) {
          float v = bov[ct]; f32x4 tv = {v, v, v, v}; pacc[rtl][ct] = tv;
        }
#pragma unroll
      for (int kc = 0; kc < 2; ++kc) {
        short8 hA0 = *(const short8*)(hs + (0*16 + lo)*72 + kc*32 + hi*8);
        short8 hA1 = *(const short8*)(hs + (1*16 + lo)*72 + kc*32 + hi*8);
        pacc[0][0] = __builtin_amdgcn_mfma_f32_16x16x32_bf16(hA0, wo[0][kc], pacc[0][0], 0, 0, 0);
        pacc[0][1] = __builtin_amdgcn_mfma_f32_16x16x32_bf16(hA0, wo[1][kc], pacc[0][1], 0, 0, 0);
        pacc[1][0] = __builtin_amdgcn_mfma_f32_16x16x32_bf16(hA1, wo[0][kc], pacc[1][0], 0, 0, 0);
        pacc[1][1] = __builtin_amdgcn_mfma_f32_16x16x32_bf16(hA1, wo[1][kc], pacc[1][1], 0, 0, 0);
      }
#pragma unroll
      for (int rtl = 0; rtl < 2; ++rtl)
#pragma unroll
        for (int ct = 0; ct < 2; ++ct) {
          int n = 32*wid + 16*ct + lo;
#pragma unroll
          for (int p = 0; p < 4; ++p) {
            int b = 32*g + rtl*16 + hi*4 + p;
            size_t idx = ((size_t)b * 256 + (t - 256)) * 128 + n;
            float v = fminf(64.f, fmaxf(-64.f, pacc[rtl][ct][p]));
            if (bf) ((u16*)out_)[idx] = f2bf(v);
            else    ((float*)out_)[idx] = v;
          }
        }
    }
  }
}

extern "C" void kernel_launch(void* const* d_in, const int* in_sizes, int n_in,
                              void* d_out, int out_size, void* d_ws, size_t ws_size,
                              hipStream_t stream)
{
  char* ws = (char*)d_ws;
  int* pflag = (int*)ws;                 // 4KB: per-wave producer flags
  int* cflag = (int*)(ws + 4096);        // 4KB: per-wave consumer flags
  u64* xbuf  = (u64*)(ws + 16384);       // handoff ring

  size_t avail = (ws_size > 16384) ? ws_size - 16384 : 0;
  size_t per_ring = (size_t)63 * 4 * 4096;   // one ring slot across all (l,g) edges
  int RING = 1;
  while (RING < 64 && (size_t)RING * 2 * per_ring <= avail) RING *= 2;

  hipMemsetAsync(ws, 0, 16384, stream);  // zero flags every launch
  gru_pipeline<<<256, 256, 0, stream>>>(
      d_in[0], d_in[1], d_in[2], d_in[3], d_in[4], d_in[5],
      d_in[6], d_in[7], d_in[8], d_in[9], d_in[10], d_in[11], d_in[12],
      d_out, pflag, cflag, xbuf, RING);
  (void)in_sizes; (void)n_in; (void)out_size;
}

// Round 5
// 6693.859 us; speedup vs baseline: 2.9063x; 2.0427x over previous
//
#include <hip/hip_runtime.h>
#include <stdint.h>

typedef uint16_t u16;
typedef unsigned long long u64;
typedef __attribute__((ext_vector_type(8))) short short8;   // 8 x bf16 bits (4 VGPRs)
typedef __attribute__((ext_vector_type(4))) float f32x4;

#define SCOPE __HIP_MEMORY_SCOPE_AGENT

static __device__ __forceinline__ float bf2f(u16 b) {
  union { uint32_t u; float f; } x; x.u = ((uint32_t)b) << 16; return x.f;
}
static __device__ __forceinline__ u16 f2bf(float f) {
  union { float f; uint32_t u; } x; x.f = f;
  uint32_t u = x.u;
  u += 0x7fffu + ((u >> 16) & 1u);   // RTNE
  return (u16)(u >> 16);
}
static __device__ __forceinline__ float sigm(float x) {
  x = fminf(30.f, fmaxf(-30.f, x));
  return __builtin_amdgcn_rcpf(1.f + __expf(-x));
}
static __device__ __forceinline__ float tanhf_(float x) {
  x = fminf(15.f, fmaxf(-15.f, x));
  return 1.f - 2.f * __builtin_amdgcn_rcpf(1.f + __expf(2.f * x));
}

// Persistent pipelined GRU. One WG per (layer L in 0..63, chunk g in 0..3 of 32 batch rows).
// t = 0..511: enc steps 0..255 (enc weights), dec 256..511 (dec weights), h carried.
// Layer-63 blocks also apply the output projection per step, writing d_out directly.
// R5 change: CHUNKED handoff. Flags (release) published once per CH steps, not per
// step — R4 executed a release (s_waitcnt vmcnt(0) drain to MALL) in EVERY wave EVERY
// step, serializing ~µs-scale coherence drains into all 512 steps (MfmaUtil 0.6%,
// VALUBusy 3.9%). Ring holds R=2*CH slots; records still stream per-step (relaxed),
// consumer register-prefetches next step's record inside the chunk.
// MFMA 16x16x32 bf16 layouts (m89-verified):
//   A: lane holds A[m=lane&15][k=(lane>>4)*8 + j]
//   B: lane holds B[k=(lane>>4)*8 + j][n=lane&15]  (8 contiguous k of row n of W, W=(N,K) row-major)
//   C/D: reg p -> (row=(lane>>4)*4+p, col=lane&15)
__global__ __launch_bounds__(256, 1) void gru_pipeline(
    const void* ctx_,
    const void* eWih0_, const void* eWih_, const void* eWhh_,
    const void* ebih_,  const void* ebhh_,
    const void* dWih0_, const void* dWih_, const void* dWhh_,
    const void* dbih_,  const void* dbhh_,
    const void* Wo_,    const void* bo_,   void* out_,
    int* __restrict__ pflag, int* __restrict__ cflag,
    u64* __restrict__ xbuf, int R, int CH)
{
  const int tid  = threadIdx.x;
  const int lane = tid & 63;
  const int wid  = tid >> 6;
  const int rt   = wid >> 1;      // row-tile (16 batch rows each)
  const int cs   = wid & 1;       // gate-col half
  const int lo   = lane & 15;
  const int hi   = lane >> 4;
  const int blk  = blockIdx.x;
  const int L    = blk >> 2;
  const int g    = blk & 3;
  const int KIN  = (L == 0) ? 128 : 64;
  const int NKC  = KIN >> 5;
  const int RM   = R - 1;         // R is a power of two
  const int RC   = R / CH;        // ring slack in chunks (>=1)
  const int NCH  = 512 / CH;

  __shared__ __align__(16) u16 hb[2][32 * 72];
  __shared__ __align__(16) u16 xst[32 * 72];
  __shared__ int s_cnt;
  if (tid == 0) s_cnt = 0;
  for (int i = tid; i < 2 * 32 * 72; i += 256) (&hb[0][0])[i] = 0;
  for (int i = tid; i < 32 * 72; i += 256) xst[i] = 0;
  __syncthreads();
  {  // dtype probe: even u16s of enc_bih (12288 elems either way)
    u16 v = ((const u16*)ebih_)[2 * tid];
    int e = (v >> 7) & 0xFF;
    if (e >= 100 && e <= 126) atomicAdd(&s_cnt, 1);
  }
  __syncthreads();
  const bool bf = (s_cnt >= 128);   // true: tensors are bf16; false: fp32

  auto ld8 = [&](const void* p, int idx) -> short8 {   // 8 elems -> bf16 frag
    if (bf) return *(const short8*)((const u16*)p + idx);
    const float* f = (const float*)p + idx;
    short8 r;
#pragma unroll
    for (int j = 0; j < 8; ++j) r[j] = (short)f2bf(f[j]);
    return r;
  };
  auto ld1 = [&](const void* p, int idx) -> float {
    return bf ? bf2f(((const u16*)p)[idx]) : ((const float*)p)[idx];
  };

  int T[6];
  T[0] = 2*cs; T[1] = 2*cs+1; T[2] = 4+2*cs; T[3] = 5+2*cs; T[4] = 8+2*cs; T[5] = 9+2*cs;

  short8 zf8 = {0,0,0,0,0,0,0,0};
  short8 wh[6][2];
  short8 wi[6][4];
  short8 wo[2][2];                 // layer-63 only: Wo B-frags
  float  bov[2] = {0.f, 0.f};
  float brz[4], bin2[2], bhn2[2];
#pragma unroll
  for (int a = 0; a < 6; ++a) { wh[a][0]=zf8; wh[a][1]=zf8;
#pragma unroll
    for (int b = 0; b < 4; ++b) wi[a][b]=zf8; }
  wo[0][0]=wo[0][1]=wo[1][0]=wo[1][1]=zf8;

  auto load_phase = [&](int ph) {
    const void* WH = ph ? dWhh_ : eWhh_;
    const void* WI = (L == 0) ? (ph ? dWih0_ : eWih0_) : (ph ? dWih_ : eWih_);
    const int  wbase = L * 192 * 64;
    const int  ibase = (L == 0) ? 0 : (L - 1) * 192 * 64;
    const void* bi = ph ? dbih_ : ebih_;
    const void* bh = ph ? dbhh_ : ebhh_;
#pragma unroll
    for (int ti = 0; ti < 6; ++ti) {
#pragma unroll
      for (int kc = 0; kc < 2; ++kc)
        wh[ti][kc] = ld8(WH, wbase + (T[ti]*16 + lo)*64 + kc*32 + hi*8);
#pragma unroll
      for (int kc = 0; kc < 4; ++kc)
        if (kc < NKC)
          wi[ti][kc] = ld8(WI, ibase + (T[ti]*16 + lo)*KIN + kc*32 + hi*8);
    }
#pragma unroll
    for (int q = 0; q < 4; ++q)
      brz[q] = ld1(bi, L*192 + T[q]*16 + lo) + ld1(bh, L*192 + T[q]*16 + lo);
#pragma unroll
    for (int q = 0; q < 2; ++q) {
      bin2[q] = ld1(bi, L*192 + T[4+q]*16 + lo);
      bhn2[q] = ld1(bh, L*192 + T[4+q]*16 + lo);
    }
  };
  load_phase(0);
  if (L == 63) {
#pragma unroll
    for (int ct = 0; ct < 2; ++ct) {
      int n = 32*wid + 16*ct + lo;
#pragma unroll
      for (int kc = 0; kc < 2; ++kc)
        wo[ct][kc] = ld8(Wo_, n*64 + kc*32 + hi*8);
      bov[ct] = ld1(bo_, n);
    }
  }

  float hprev[2][4];
#pragma unroll
  for (int q = 0; q < 2; ++q)
#pragma unroll
    for (int p = 0; p < 4; ++p) hprev[q][p] = 0.f;

  short8 xf[4] = {zf8, zf8, zf8, zf8};
  const int brow = 32*g + rt*16 + lo;
  if (L == 0) {
#pragma unroll
    for (int kc = 0; kc < 4; ++kc)
      xf[kc] = ld8(ctx_, (brow * 256 + 0) * 128 + kc*32 + hi*8);
  }

  const int eIn  = (L > 0 ? L - 1 : 0) * 4 + g;   // deref'd only when L>0
  const int eOut = (L < 63 ? L : 62) * 4 + g;     // deref'd only when L<63
  const u64* recin  = xbuf + (size_t)eIn  * R * 512;
  u64*       recout = xbuf + (size_t)eOut * R * 512;
  int* fin   = pflag + eIn * 4;
  int* fout  = pflag + eOut * 4;
  int* cself = cflag + (L * 4 + g) * 4;
  int* cnext = cflag + ((L < 63 ? L + 1 : 63) * 4 + g) * 4;

  int budget = 1 << 22;   // anti-hang: waits degrade to no-ops if exhausted

  __syncthreads();

  for (int k = 0; k < NCH; ++k) {
    const int t0 = k * CH;
    if (t0 == 256) load_phase(1);

    // ---- once-per-chunk sync: wave 0 / lanes 0-3 poll; others gated by Bc
    if (wid == 0) {
      if (L < 63 && k >= RC) {   // ring backpressure (chunk units)
        while (budget > 0) {
          int v = (lane < 4) ? __hip_atomic_load(cnext + lane, __ATOMIC_ACQUIRE, SCOPE)
                             : 0x7fffffff;
          if (__all(v >= k + 1 - RC)) break;
          --budget; __builtin_amdgcn_s_sleep(1);
        }
      }
      if (L > 0) {               // producer published chunk k
        while (budget > 0) {
          int v = (lane < 4) ? __hip_atomic_load(fin + lane, __ATOMIC_ACQUIRE, SCOPE)
                             : 0x7fffffff;
          if (__all(v >= k + 1)) break;
          --budget; __builtin_amdgcn_s_sleep(1);
        }
      }
    }
    __syncthreads();   // Bc: chunk-k records visible to all waves

    // prime record prefetch for first step of the chunk
    u64 pa = 0, pb = 0;
    if (L > 0) {
      const u64* rec = recin + (size_t)(t0 & RM) * 512 + tid * 2;
      pa = __hip_atomic_load(rec,     __ATOMIC_RELAXED, SCOPE);
      pb = __hip_atomic_load(rec + 1, __ATOMIC_RELAXED, SCOPE);
    }

    for (int tt = 0; tt < CH; ++tt) {
      const int t = t0 + tt;

      // ---- stage x_t (prefetched regs) -> LDS; kick prefetch for t+1
      if (L > 0) {
        const int row = (tid >> 7) * 16 + ((tid >> 4) & 3) * 4;
        const int col = ((tid >> 6) & 1) * 32 + (tid & 15);
#pragma unroll
        for (int p = 0; p < 4; ++p) {
          xst[(row + p) * 72 + col]      = (u16)(pa >> (16 * p));
          xst[(row + p) * 72 + col + 16] = (u16)(pb >> (16 * p));
        }
        if (tt + 1 < CH) {
          const u64* rec = recin + (size_t)((t + 1) & RM) * 512 + tid * 2;
          pa = __hip_atomic_load(rec,     __ATOMIC_RELAXED, SCOPE);
          pb = __hip_atomic_load(rec + 1, __ATOMIC_RELAXED, SCOPE);
        }
      }
      __syncthreads();   // Ba: xst(t) writes -> reads; hb(t-1) writes -> reads

      // ---- accumulators seeded with biases
      f32x4 acc_rz[4], acc_in[2], acc_hn[2];
#pragma unroll
      for (int q = 0; q < 4; ++q) { float v = brz[q];  f32x4 tv = {v, v, v, v}; acc_rz[q] = tv; }
#pragma unroll
      for (int q = 0; q < 2; ++q) { float v = bin2[q]; f32x4 tv = {v, v, v, v}; acc_in[q] = tv;
                                    float w = bhn2[q]; f32x4 tw = {w, w, w, w}; acc_hn[q] = tw; }

      // ---- gh = h_{t-1} @ Whh^T
      const u16* hsrc = hb[(t + 1) & 1];
#pragma unroll
      for (int kc = 0; kc < 2; ++kc) {
        short8 hA = *(const short8*)(hsrc + (rt*16 + lo)*72 + kc*32 + hi*8);
        acc_rz[0] = __builtin_amdgcn_mfma_f32_16x16x32_bf16(hA, wh[0][kc], acc_rz[0], 0, 0, 0);
        acc_rz[1] = __builtin_amdgcn_mfma_f32_16x16x32_bf16(hA, wh[1][kc], acc_rz[1], 0, 0, 0);
        acc_rz[2] = __builtin_amdgcn_mfma_f32_16x16x32_bf16(hA, wh[2][kc], acc_rz[2], 0, 0, 0);
        acc_rz[3] = __builtin_amdgcn_mfma_f32_16x16x32_bf16(hA, wh[3][kc], acc_rz[3], 0, 0, 0);
        acc_hn[0] = __builtin_amdgcn_mfma_f32_16x16x32_bf16(hA, wh[4][kc], acc_hn[0], 0, 0, 0);
        acc_hn[1] = __builtin_amdgcn_mfma_f32_16x16x32_bf16(hA, wh[5][kc], acc_hn[1], 0, 0, 0);
      }

      // ---- x A-frags (L>0 from xst, already barrier-ordered)
      if (L > 0) {
#pragma unroll
        for (int kc = 0; kc < 2; ++kc)
          xf[kc] = *(const short8*)(xst + (rt*16 + lo)*72 + kc*32 + hi*8);
      }

      // ---- gi = x_t @ Wih^T  (dec_in[:,0] == 0 -> skip at t==256 for layer 0)
      if (!(L == 0 && t == 256)) {
#pragma unroll
        for (int kc = 0; kc < 4; ++kc) {
          if (kc < NKC) {
            acc_rz[0] = __builtin_amdgcn_mfma_f32_16x16x32_bf16(xf[kc], wi[0][kc], acc_rz[0], 0, 0, 0);
            acc_rz[1] = __builtin_amdgcn_mfma_f32_16x16x32_bf16(xf[kc], wi[1][kc], acc_rz[1], 0, 0, 0);
            acc_rz[2] = __builtin_amdgcn_mfma_f32_16x16x32_bf16(xf[kc], wi[2][kc], acc_rz[2], 0, 0, 0);
            acc_rz[3] = __builtin_amdgcn_mfma_f32_16x16x32_bf16(xf[kc], wi[3][kc], acc_rz[3], 0, 0, 0);
            acc_in[0] = __builtin_amdgcn_mfma_f32_16x16x32_bf16(xf[kc], wi[4][kc], acc_in[0], 0, 0, 0);
            acc_in[1] = __builtin_amdgcn_mfma_f32_16x16x32_bf16(xf[kc], wi[5][kc], acc_in[1], 0, 0, 0);
          }
        }
      }

      // ---- layer 0: prefetch x for t+1
      if (L == 0) {
        int tn = t + 1;
        int tt2 = (tn < 256) ? tn : ((tn == 256) ? 0 : tn - 257);
#pragma unroll
        for (int kc = 0; kc < 4; ++kc)
          xf[kc] = ld8(ctx_, (brow * 256 + tt2) * 128 + kc*32 + hi*8);
      }

      // ---- gates (fp32; reg p -> batch row hi*4+p). |h|<=1 invariant; clamp = no-op guard
      u16 hbits[2][4];
#pragma unroll
      for (int q = 0; q < 2; ++q) {
#pragma unroll
        for (int p = 0; p < 4; ++p) {
          float r = sigm(acc_rz[q][p]);
          float z = sigm(acc_rz[2 + q][p]);
          float n = tanhf_(acc_in[q][p] + r * acc_hn[q][p]);
          float h = n + z * (hprev[q][p] - n);
          h = fminf(1.f, fmaxf(-1.f, h));
          hprev[q][p] = h;
          hbits[q][p] = f2bf(h);
        }
      }

      // ---- h_t -> LDS
      u16* hd = hb[t & 1];
#pragma unroll
      for (int q = 0; q < 2; ++q)
#pragma unroll
        for (int p = 0; p < 4; ++p)
          hd[(rt*16 + hi*4 + p) * 72 + cs*32 + q*16 + lo] = hbits[q][p];

      // ---- stream h_t record (relaxed; drained once per chunk by the release)
      if (L < 63) {
        u64 da = (u64)hbits[0][0] | ((u64)hbits[0][1] << 16) | ((u64)hbits[0][2] << 32) | ((u64)hbits[0][3] << 48);
        u64 db = (u64)hbits[1][0] | ((u64)hbits[1][1] << 16) | ((u64)hbits[1][2] << 32) | ((u64)hbits[1][3] << 48);
        u64* ro = recout + (size_t)(t & RM) * 512 + tid * 2;
        __hip_atomic_store(ro,     da, __ATOMIC_RELAXED, SCOPE);
        __hip_atomic_store(ro + 1, db, __ATOMIC_RELAXED, SCOPE);
      }
      __syncthreads();   // Bb: hb(t) writes -> next step / projection reads

      // ---- layer 63, decoder steps: fused output projection from full hb[t&1]
      if (L == 63 && t >= 256) {
        const u16* hs = hb[t & 1];
        f32x4 pacc[2][2];
#pragma unroll
        for (int rtl = 0; rtl < 2; ++rtl)
#pragma unroll
          for (int ct = 0; ct < 2; ++ct) {
            float v = bov[ct]; f32x4 tv = {v, v, v, v}; pacc[rtl][ct] = tv;
          }
#pragma unroll
        for (int kc = 0; kc < 2; ++kc) {
          short8 hA0 = *(const short8*)(hs + (0*16 + lo)*72 + kc*32 + hi*8);
          short8 hA1 = *(const short8*)(hs + (1*16 + lo)*72 + kc*32 + hi*8);
          pacc[0][0] = __builtin_amdgcn_mfma_f32_16x16x32_bf16(hA0, wo[0][kc], pacc[0][0], 0, 0, 0);
          pacc[0][1] = __builtin_amdgcn_mfma_f32_16x16x32_bf16(hA0, wo[1][kc], pacc[0][1], 0, 0, 0);
          pacc[1][0] = __builtin_amdgcn_mfma_f32_16x16x32_bf16(hA1, wo[0][kc], pacc[1][0], 0, 0, 0);
          pacc[1][1] = __builtin_amdgcn_mfma_f32_16x16x32_bf16(hA1, wo[1][kc], pacc[1][1], 0, 0, 0);
        }
#pragma unroll
        for (int rtl = 0; rtl < 2; ++rtl)
#pragma unroll
          for (int ct = 0; ct < 2; ++ct) {
            int n = 32*wid + 16*ct + lo;
#pragma unroll
            for (int p = 0; p < 4; ++p) {
              int b = 32*g + rtl*16 + hi*4 + p;
              size_t idx = ((size_t)b * 256 + (t - 256)) * 128 + n;
              float v = fminf(64.f, fmaxf(-64.f, pacc[rtl][ct][p]));
              if (bf) ((u16*)out_)[idx] = f2bf(v);
              else    ((float*)out_)[idx] = v;
            }
          }
      }
    }

    // ---- once-per-chunk publication (per-WAVE release: orders that wave's
    // record stores / loads; the vmcnt(0) drain now amortizes over CH steps)
    if (L < 63 && lane == 0)
      __hip_atomic_store(fout + wid, k + 1, __ATOMIC_RELEASE, SCOPE);
    if (L > 0 && lane == 0)
      __hip_atomic_store(cself + wid, k + 1, __ATOMIC_RELEASE, SCOPE);
  }
}

extern "C" void kernel_launch(void* const* d_in, const int* in_sizes, int n_in,
                              void* d_out, int out_size, void* d_ws, size_t ws_size,
                              hipStream_t stream)
{
  char* ws = (char*)d_ws;
  int* pflag = (int*)ws;                 // 4KB: per-wave producer flags
  int* cflag = (int*)(ws + 4096);        // 4KB: per-wave consumer flags
  u64* xbuf  = (u64*)(ws + 16384);       // handoff ring

  size_t avail = (ws_size > 16384) ? ws_size - 16384 : 0;
  size_t per_slot = (size_t)63 * 4 * 4096;   // one ring slot across all (l,g) edges
  int R = 1;
  for (int r = 32; r >= 1; r >>= 1)
    if ((size_t)r * per_slot <= avail) { R = r; break; }
  int CH = (R >= 2) ? ((R / 2 > 16) ? 16 : R / 2) : 1;   // CH | 256 guaranteed

  hipMemsetAsync(ws, 0, 16384, stream);  // zero flags every launch
  gru_pipeline<<<256, 256, 0, stream>>>(
      d_in[0], d_in[1], d_in[2], d_in[3], d_in[4], d_in[5],
      d_in[6], d_in[7], d_in[8], d_in[9], d_in[10], d_in[11], d_in[12],
      d_out, pflag, cflag, xbuf, R, CH);
  (void)in_sizes; (void)n_in; (void)out_size;
}

// Round 6
// 5961.678 us; speedup vs baseline: 3.2633x; 1.1228x over previous
//
#include <hip/hip_runtime.h>
#include <stdint.h>

typedef uint16_t u16;
typedef unsigned long long u64;
typedef __attribute__((ext_vector_type(8))) short short8;   // 8 x bf16 bits (4 VGPRs)
typedef __attribute__((ext_vector_type(4))) float f32x4;

#define SCOPE __HIP_MEMORY_SCOPE_AGENT

static __device__ __forceinline__ float bf2f(u16 b) {
  union { uint32_t u; float f; } x; x.u = ((uint32_t)b) << 16; return x.f;
}
static __device__ __forceinline__ u16 f2bf(float f) {
  union { float f; uint32_t u; } x; x.f = f;
  uint32_t u = x.u;
  u += 0x7fffu + ((u >> 16) & 1u);   // RTNE
  return (u16)(u >> 16);
}
static __device__ __forceinline__ float sigm(float x) {
  x = fminf(30.f, fmaxf(-30.f, x));
  return __builtin_amdgcn_rcpf(1.f + __expf(-x));
}
static __device__ __forceinline__ float tanhf_(float x) {
  x = fminf(15.f, fmaxf(-15.f, x));
  return 1.f - 2.f * __builtin_amdgcn_rcpf(1.f + __expf(2.f * x));
}
// LDS-only barrier: does NOT drain vmcnt — global loads/stores stay in flight
// across steps (the per-step vmcnt(0) drain in __syncthreads was the 4.4µs/step
// stall in R5: it synchronously exposed the MALL round-trip every step).
static __device__ __forceinline__ void lds_barrier() {
  asm volatile("s_waitcnt lgkmcnt(0)\n\ts_barrier" ::: "memory");
}

// Persistent pipelined GRU. One WG per (layer L in 0..63, chunk g in 0..3 of 32 batch rows).
// t = 0..511: enc steps 0..255 (enc weights), dec 256..511 (dec weights), h carried.
// Layer-63 blocks also apply the output projection (shifted one step late), writing
// d_out directly. Cross-layer handoff: 4KB/step register-dump records, agent-scope
// atomics in an R-slot ring; flags published once per CH-step chunk (release =
// vmcnt(0) drain, amortized). R6: single raw LDS barrier per step; distance-2
// record prefetch primed per chunk.
// MFMA 16x16x32 bf16 layouts (m89-verified):
//   A: lane holds A[m=lane&15][k=(lane>>4)*8 + j]
//   B: lane holds B[k=(lane>>4)*8 + j][n=lane&15]  (8 contiguous k of row n of W, W=(N,K) row-major)
//   C/D: reg p -> (row=(lane>>4)*4+p, col=lane&15)
__global__ __launch_bounds__(256, 1) void gru_pipeline(
    const void* ctx_,
    const void* eWih0_, const void* eWih_, const void* eWhh_,
    const void* ebih_,  const void* ebhh_,
    const void* dWih0_, const void* dWih_, const void* dWhh_,
    const void* dbih_,  const void* dbhh_,
    const void* Wo_,    const void* bo_,   void* out_,
    int* __restrict__ pflag, int* __restrict__ cflag,
    u64* __restrict__ xbuf, int R, int CH)
{
  const int tid  = threadIdx.x;
  const int lane = tid & 63;
  const int wid  = tid >> 6;
  const int rt   = wid >> 1;      // row-tile (16 batch rows each)
  const int cs   = wid & 1;       // gate-col half
  const int lo   = lane & 15;
  const int hi   = lane >> 4;
  const int blk  = blockIdx.x;
  const int L    = blk >> 2;
  const int g    = blk & 3;
  const int KIN  = (L == 0) ? 128 : 64;
  const int NKC  = KIN >> 5;
  const int RM   = R - 1;         // R is a power of two
  const int RC   = (R / CH) > 0 ? (R / CH) : 1;  // ring slack in chunks
  const int NCH  = 512 / CH;

  __shared__ __align__(16) u16 hb[2][32 * 72];
  __shared__ __align__(16) u16 xst[2][32 * 72];
  __shared__ int s_cnt;
  if (tid == 0) s_cnt = 0;
  for (int i = tid; i < 2 * 32 * 72; i += 256) (&hb[0][0])[i] = 0;
  for (int i = tid; i < 2 * 32 * 72; i += 256) (&xst[0][0])[i] = 0;
  __syncthreads();
  {  // dtype probe: even u16s of enc_bih (12288 elems either way)
    u16 v = ((const u16*)ebih_)[2 * tid];
    int e = (v >> 7) & 0xFF;
    if (e >= 100 && e <= 126) atomicAdd(&s_cnt, 1);
  }
  __syncthreads();
  const bool bf = (s_cnt >= 128);   // true: tensors are bf16; false: fp32

  auto ld8 = [&](const void* p, int idx) -> short8 {   // 8 elems -> bf16 frag
    if (bf) return *(const short8*)((const u16*)p + idx);
    const float* f = (const float*)p + idx;
    short8 r;
#pragma unroll
    for (int j = 0; j < 8; ++j) r[j] = (short)f2bf(f[j]);
    return r;
  };
  auto ld1 = [&](const void* p, int idx) -> float {
    return bf ? bf2f(((const u16*)p)[idx]) : ((const float*)p)[idx];
  };

  int T[6];
  T[0] = 2*cs; T[1] = 2*cs+1; T[2] = 4+2*cs; T[3] = 5+2*cs; T[4] = 8+2*cs; T[5] = 9+2*cs;

  short8 zf8 = {0,0,0,0,0,0,0,0};
  short8 wh[6][2];
  short8 wi[6][4];
  short8 wo[2][2];                 // layer-63 only: Wo B-frags
  float  bov[2] = {0.f, 0.f};
  float brz[4], bin2[2], bhn2[2];
#pragma unroll
  for (int a = 0; a < 6; ++a) { wh[a][0]=zf8; wh[a][1]=zf8;
#pragma unroll
    for (int b = 0; b < 4; ++b) wi[a][b]=zf8; }
  wo[0][0]=wo[0][1]=wo[1][0]=wo[1][1]=zf8;

  auto load_phase = [&](int ph) {
    const void* WH = ph ? dWhh_ : eWhh_;
    const void* WI = (L == 0) ? (ph ? dWih0_ : eWih0_) : (ph ? dWih_ : eWih_);
    const int  wbase = L * 192 * 64;
    const int  ibase = (L == 0) ? 0 : (L - 1) * 192 * 64;
    const void* bi = ph ? dbih_ : ebih_;
    const void* bh = ph ? dbhh_ : ebhh_;
#pragma unroll
    for (int ti = 0; ti < 6; ++ti) {
#pragma unroll
      for (int kc = 0; kc < 2; ++kc)
        wh[ti][kc] = ld8(WH, wbase + (T[ti]*16 + lo)*64 + kc*32 + hi*8);
#pragma unroll
      for (int kc = 0; kc < 4; ++kc)
        if (kc < NKC)
          wi[ti][kc] = ld8(WI, ibase + (T[ti]*16 + lo)*KIN + kc*32 + hi*8);
    }
#pragma unroll
    for (int q = 0; q < 4; ++q)
      brz[q] = ld1(bi, L*192 + T[q]*16 + lo) + ld1(bh, L*192 + T[q]*16 + lo);
#pragma unroll
    for (int q = 0; q < 2; ++q) {
      bin2[q] = ld1(bi, L*192 + T[4+q]*16 + lo);
      bhn2[q] = ld1(bh, L*192 + T[4+q]*16 + lo);
    }
  };
  load_phase(0);
  if (L == 63) {
#pragma unroll
    for (int ct = 0; ct < 2; ++ct) {
      int n = 32*wid + 16*ct + lo;
#pragma unroll
      for (int kc = 0; kc < 2; ++kc)
        wo[ct][kc] = ld8(Wo_, n*64 + kc*32 + hi*8);
      bov[ct] = ld1(bo_, n);
    }
  }

  // layer-63 projection of step tprev from full-h LDS buffer hs
  auto do_proj = [&](int tprev, const u16* hs) {
    f32x4 pacc[2][2];
#pragma unroll
    for (int rtl = 0; rtl < 2; ++rtl)
#pragma unroll
      for (int ct = 0; ct < 2; ++ct) {
        float v = bov[ct]; f32x4 tv = {v, v, v, v}; pacc[rtl][ct] = tv;
      }
#pragma unroll
    for (int kc = 0; kc < 2; ++kc) {
      short8 hA0 = *(const short8*)(hs + (0*16 + lo)*72 + kc*32 + hi*8);
      short8 hA1 = *(const short8*)(hs + (1*16 + lo)*72 + kc*32 + hi*8);
      pacc[0][0] = __builtin_amdgcn_mfma_f32_16x16x32_bf16(hA0, wo[0][kc], pacc[0][0], 0, 0, 0);
      pacc[0][1] = __builtin_amdgcn_mfma_f32_16x16x32_bf16(hA0, wo[1][kc], pacc[0][1], 0, 0, 0);
      pacc[1][0] = __builtin_amdgcn_mfma_f32_16x16x32_bf16(hA1, wo[0][kc], pacc[1][0], 0, 0, 0);
      pacc[1][1] = __builtin_amdgcn_mfma_f32_16x16x32_bf16(hA1, wo[1][kc], pacc[1][1], 0, 0, 0);
    }
#pragma unroll
    for (int rtl = 0; rtl < 2; ++rtl)
#pragma unroll
      for (int ct = 0; ct < 2; ++ct) {
        int n = 32*wid + 16*ct + lo;
#pragma unroll
        for (int p = 0; p < 4; ++p) {
          int b = 32*g + rtl*16 + hi*4 + p;
          size_t idx = ((size_t)b * 256 + (tprev - 256)) * 128 + n;
          float v = fminf(64.f, fmaxf(-64.f, pacc[rtl][ct][p]));
          if (bf) ((u16*)out_)[idx] = f2bf(v);
          else    ((float*)out_)[idx] = v;
        }
      }
  };

  float hprev[2][4];
#pragma unroll
  for (int q = 0; q < 2; ++q)
#pragma unroll
    for (int p = 0; p < 4; ++p) hprev[q][p] = 0.f;

  short8 xf[4] = {zf8, zf8, zf8, zf8};
  const int brow = 32*g + rt*16 + lo;
  if (L == 0) {
#pragma unroll
    for (int kc = 0; kc < 4; ++kc)
      xf[kc] = ld8(ctx_, (brow * 256 + 0) * 128 + kc*32 + hi*8);
  }

  const int eIn  = (L > 0 ? L - 1 : 0) * 4 + g;   // deref'd only when L>0
  const int eOut = (L < 63 ? L : 62) * 4 + g;     // deref'd only when L<63
  const u64* recin  = xbuf + (size_t)eIn  * R * 512;
  u64*       recout = xbuf + (size_t)eOut * R * 512;
  int* fin   = pflag + eIn * 4;
  int* fout  = pflag + eOut * 4;
  int* cself = cflag + (L * 4 + g) * 4;
  int* cnext = cflag + ((L < 63 ? L + 1 : 63) * 4 + g) * 4;

  int budget = 1 << 22;   // anti-hang: waits degrade to no-ops if exhausted

  // stage scatter coords (record layout, verified R3-R5)
  const int srow = (tid >> 7) * 16 + ((tid >> 4) & 3) * 4;
  const int scol = ((tid >> 6) & 1) * 32 + (tid & 15);

  __syncthreads();

  for (int k = 0; k < NCH; ++k) {
    const int t0 = k * CH;
    if (t0 == 256) load_phase(1);

    // ---- once-per-chunk sync: wave 0 / lanes 0-3 poll; others gated by Bc
    if (wid == 0) {
      if (L < 63 && k >= RC) {   // ring backpressure (chunk units)
        while (budget > 0) {
          int v = (lane < 4) ? __hip_atomic_load(cnext + lane, __ATOMIC_ACQUIRE, SCOPE)
                             : 0x7fffffff;
          if (__all(v >= k + 1 - RC)) break;
          --budget; __builtin_amdgcn_s_sleep(2);
        }
      }
      if (L > 0) {               // producer published chunk k
        while (budget > 0) {
          int v = (lane < 4) ? __hip_atomic_load(fin + lane, __ATOMIC_ACQUIRE, SCOPE)
                             : 0x7fffffff;
          if (__all(v >= k + 1)) break;
          --budget; __builtin_amdgcn_s_sleep(2);
        }
      }
    }
    __syncthreads();   // Bc: chunk-k records visible; once per chunk, drain ~free

    // ---- prime distance-2 record prefetch
    u64 p0a = 0, p0b = 0, p1a = 0, p1b = 0;
    if (L > 0) {
      const u64* r0 = recin + (size_t)(t0 & RM) * 512 + tid * 2;
      p0a = __hip_atomic_load(r0,     __ATOMIC_RELAXED, SCOPE);
      p0b = __hip_atomic_load(r0 + 1, __ATOMIC_RELAXED, SCOPE);
      if (CH > 1) {
        const u64* r1 = recin + (size_t)((t0 + 1) & RM) * 512 + tid * 2;
        p1a = __hip_atomic_load(r1,     __ATOMIC_RELAXED, SCOPE);
        p1b = __hip_atomic_load(r1 + 1, __ATOMIC_RELAXED, SCOPE);
      }
    }

    for (int tt = 0; tt < CH; ++tt) {
      const int t = t0 + tt;

      // ---- stage x_t (prefetched ~2 steps ago) -> xst[t&1]; refill prefetch reg
      if (L > 0) {
        u64 a = (tt & 1) ? p1a : p0a;
        u64 b = (tt & 1) ? p1b : p0b;
        u16* xd = xst[t & 1];
#pragma unroll
        for (int p = 0; p < 4; ++p) {
          xd[(srow + p) * 72 + scol]      = (u16)(a >> (16 * p));
          xd[(srow + p) * 72 + scol + 16] = (u16)(b >> (16 * p));
        }
        if (tt + 2 < CH) {
          const u64* rn = recin + (size_t)((t + 2) & RM) * 512 + tid * 2;
          u64 na = __hip_atomic_load(rn,     __ATOMIC_RELAXED, SCOPE);
          u64 nb = __hip_atomic_load(rn + 1, __ATOMIC_RELAXED, SCOPE);
          if (tt & 1) { p1a = na; p1b = nb; } else { p0a = na; p0b = nb; }
        }
      }

      lds_barrier();   // B1: xst(t) + hb(t-1) writes visible; NO vmcnt drain

      // ---- layer 63: projection of step t-1 (h_{t-1} lives in hb[(t+1)&1])
      if (L == 63 && t >= 257) do_proj(t - 1, hb[(t + 1) & 1]);

      // ---- accumulators seeded with biases
      f32x4 acc_rz[4], acc_in[2], acc_hn[2];
#pragma unroll
      for (int q = 0; q < 4; ++q) { float v = brz[q];  f32x4 tv = {v, v, v, v}; acc_rz[q] = tv; }
#pragma unroll
      for (int q = 0; q < 2; ++q) { float v = bin2[q]; f32x4 tv = {v, v, v, v}; acc_in[q] = tv;
                                    float w = bhn2[q]; f32x4 tw = {w, w, w, w}; acc_hn[q] = tw; }

      // ---- gh = h_{t-1} @ Whh^T
      const u16* hsrc = hb[(t + 1) & 1];
#pragma unroll
      for (int kc = 0; kc < 2; ++kc) {
        short8 hA = *(const short8*)(hsrc + (rt*16 + lo)*72 + kc*32 + hi*8);
        acc_rz[0] = __builtin_amdgcn_mfma_f32_16x16x32_bf16(hA, wh[0][kc], acc_rz[0], 0, 0, 0);
        acc_rz[1] = __builtin_amdgcn_mfma_f32_16x16x32_bf16(hA, wh[1][kc], acc_rz[1], 0, 0, 0);
        acc_rz[2] = __builtin_amdgcn_mfma_f32_16x16x32_bf16(hA, wh[2][kc], acc_rz[2], 0, 0, 0);
        acc_rz[3] = __builtin_amdgcn_mfma_f32_16x16x32_bf16(hA, wh[3][kc], acc_rz[3], 0, 0, 0);
        acc_hn[0] = __builtin_amdgcn_mfma_f32_16x16x32_bf16(hA, wh[4][kc], acc_hn[0], 0, 0, 0);
        acc_hn[1] = __builtin_amdgcn_mfma_f32_16x16x32_bf16(hA, wh[5][kc], acc_hn[1], 0, 0, 0);
      }

      // ---- x A-frags
      if (L > 0) {
        const u16* xs = xst[t & 1];
#pragma unroll
        for (int kc = 0; kc < 2; ++kc)
          xf[kc] = *(const short8*)(xs + (rt*16 + lo)*72 + kc*32 + hi*8);
      }

      // ---- gi = x_t @ Wih^T  (dec_in[:,0] == 0 -> skip at t==256 for layer 0)
      if (!(L == 0 && t == 256)) {
#pragma unroll
        for (int kc = 0; kc < 4; ++kc) {
          if (kc < NKC) {
            acc_rz[0] = __builtin_amdgcn_mfma_f32_16x16x32_bf16(xf[kc], wi[0][kc], acc_rz[0], 0, 0, 0);
            acc_rz[1] = __builtin_amdgcn_mfma_f32_16x16x32_bf16(xf[kc], wi[1][kc], acc_rz[1], 0, 0, 0);
            acc_rz[2] = __builtin_amdgcn_mfma_f32_16x16x32_bf16(xf[kc], wi[2][kc], acc_rz[2], 0, 0, 0);
            acc_rz[3] = __builtin_amdgcn_mfma_f32_16x16x32_bf16(xf[kc], wi[3][kc], acc_rz[3], 0, 0, 0);
            acc_in[0] = __builtin_amdgcn_mfma_f32_16x16x32_bf16(xf[kc], wi[4][kc], acc_in[0], 0, 0, 0);
            acc_in[1] = __builtin_amdgcn_mfma_f32_16x16x32_bf16(xf[kc], wi[5][kc], acc_in[1], 0, 0, 0);
          }
        }
      }

      // ---- layer 0: prefetch x for t+1 (floats across the raw barrier)
      if (L == 0) {
        int tn = t + 1;
        int tx = (tn < 256) ? tn : ((tn == 256) ? 0 : tn - 257);
#pragma unroll
        for (int kc = 0; kc < 4; ++kc)
          xf[kc] = ld8(ctx_, (brow * 256 + tx) * 128 + kc*32 + hi*8);
      }

      // ---- gates (fp32; reg p -> batch row hi*4+p). |h|<=1 invariant; clamp = no-op guard
      u16 hbits[2][4];
#pragma unroll
      for (int q = 0; q < 2; ++q) {
#pragma unroll
        for (int p = 0; p < 4; ++p) {
          float r = sigm(acc_rz[q][p]);
          float z = sigm(acc_rz[2 + q][p]);
          float n = tanhf_(acc_in[q][p] + r * acc_hn[q][p]);
          float h = n + z * (hprev[q][p] - n);
          h = fminf(1.f, fmaxf(-1.f, h));
          hprev[q][p] = h;
          hbits[q][p] = f2bf(h);
        }
      }

      // ---- h_t -> LDS (visible after next step's B1)
      u16* hd = hb[t & 1];
#pragma unroll
      for (int q = 0; q < 2; ++q)
#pragma unroll
        for (int p = 0; p < 4; ++p)
          hd[(rt*16 + hi*4 + p) * 72 + cs*32 + q*16 + lo] = hbits[q][p];

      // ---- stream h_t record (relaxed; drained once per chunk by the release)
      if (L < 63) {
        u64 da = (u64)hbits[0][0] | ((u64)hbits[0][1] << 16) | ((u64)hbits[0][2] << 32) | ((u64)hbits[0][3] << 48);
        u64 db = (u64)hbits[1][0] | ((u64)hbits[1][1] << 16) | ((u64)hbits[1][2] << 32) | ((u64)hbits[1][3] << 48);
        u64* ro = recout + (size_t)(t & RM) * 512 + tid * 2;
        __hip_atomic_store(ro,     da, __ATOMIC_RELAXED, SCOPE);
        __hip_atomic_store(ro + 1, db, __ATOMIC_RELAXED, SCOPE);
      }
    }

    // ---- once-per-chunk publication (per-WAVE release: vmcnt(0) drain of this
    // wave's record stores + reads, amortized over CH steps)
    if (L < 63 && lane == 0)
      __hip_atomic_store(fout + wid, k + 1, __ATOMIC_RELEASE, SCOPE);
    if (L > 0 && lane == 0)
      __hip_atomic_store(cself + wid, k + 1, __ATOMIC_RELEASE, SCOPE);
  }

  // ---- epilogue: projection of the final step (t = 511)
  lds_barrier();
  if (L == 63) do_proj(511, hb[1]);
}

extern "C" void kernel_launch(void* const* d_in, const int* in_sizes, int n_in,
                              void* d_out, int out_size, void* d_ws, size_t ws_size,
                              hipStream_t stream)
{
  char* ws = (char*)d_ws;
  int* pflag = (int*)ws;                 // 4KB: per-wave producer flags
  int* cflag = (int*)(ws + 4096);        // 4KB: per-wave consumer flags
  u64* xbuf  = (u64*)(ws + 16384);       // handoff ring

  size_t avail = (ws_size > 16384) ? ws_size - 16384 : 0;
  size_t per_slot = (size_t)63 * 4 * 4096;   // one ring slot across all (l,g) edges
  int R = 1;
  for (int r = 16; r >= 1; r >>= 1)
    if ((size_t)r * per_slot <= avail) { R = r; break; }
  int CH = (R >= 2) ? ((R / 2 > 8) ? 8 : R / 2) : 1;   // CH | 256 guaranteed

  hipMemsetAsync(ws, 0, 16384, stream);  // zero flags every launch
  gru_pipeline<<<256, 256, 0, stream>>>(
      d_in[0], d_in[1], d_in[2], d_in[3], d_in[4], d_in[5],
      d_in[6], d_in[7], d_in[8], d_in[9], d_in[10], d_in[11], d_in[12],
      d_out, pflag, cflag, xbuf, R, CH);
  (void)in_sizes; (void)n_in; (void)out_size;
}

// Round 7
// 4872.516 us; speedup vs baseline: 3.9927x; 1.2235x over previous
//
#include <hip/hip_runtime.h>
#include <stdint.h>

typedef uint16_t u16;
typedef unsigned long long u64;
typedef __attribute__((ext_vector_type(8))) short short8;   // 8 x bf16 bits (4 VGPRs)
typedef __attribute__((ext_vector_type(4))) float f32x4;

#define SCOPE __HIP_MEMORY_SCOPE_AGENT

static __device__ __forceinline__ float bf2f(u16 b) {
  union { uint32_t u; float f; } x; x.u = ((uint32_t)b) << 16; return x.f;
}
static __device__ __forceinline__ u16 f2bf(float f) {
  union { float f; uint32_t u; } x; x.f = f;
  uint32_t u = x.u;
  u += 0x7fffu + ((u >> 16) & 1u);   // RTNE
  return (u16)(u >> 16);
}
static __device__ __forceinline__ float sigm(float x) {
  x = fminf(30.f, fmaxf(-30.f, x));
  return __builtin_amdgcn_rcpf(1.f + __expf(-x));
}
static __device__ __forceinline__ float tanhf_(float x) {
  x = fminf(15.f, fmaxf(-15.f, x));
  return 1.f - 2.f * __builtin_amdgcn_rcpf(1.f + __expf(2.f * x));
}
// LDS-only barrier: does NOT drain vmcnt — global loads/stores stay in flight.
static __device__ __forceinline__ void lds_barrier() {
  asm volatile("s_waitcnt lgkmcnt(0)\n\ts_barrier" ::: "memory");
}

// Persistent pipelined GRU. One WG per (layer L, batch chunk g). Fit from R4-R6:
// per-chunk handoff cost D ~= 22us — 40x a MALL round trip — caused by flag
// hot-line convoying (16B/edge flags: 4 edges/line, 252 WGs polling with
// per-iteration acquire invalidates). R7: (1) 256B-padded per-edge flag lines,
// (2) relaxed polls + ONE acquire re-load on success, (3) deep ring (R<=128
// steps, RC up to 32 chunks of ack slack), CH=4.
// MFMA 16x16x32 bf16 layouts (m89-verified):
//   A: lane holds A[m=lane&15][k=(lane>>4)*8 + j]
//   B: lane holds B[k=(lane>>4)*8 + j][n=lane&15]
//   C/D: reg p -> (row=(lane>>4)*4+p, col=lane&15)
#define FSTRIDE 64   // ints per edge flag line (256B)

__global__ __launch_bounds__(256, 1) void gru_pipeline(
    const void* ctx_,
    const void* eWih0_, const void* eWih_, const void* eWhh_,
    const void* ebih_,  const void* ebhh_,
    const void* dWih0_, const void* dWih_, const void* dWhh_,
    const void* dbih_,  const void* dbhh_,
    const void* Wo_,    const void* bo_,   void* out_,
    int* __restrict__ pflag, int* __restrict__ cflag,
    u64* __restrict__ xbuf, int R, int CH)
{
  const int tid  = threadIdx.x;
  const int lane = tid & 63;
  const int wid  = tid >> 6;
  const int rt   = wid >> 1;      // row-tile (16 batch rows each)
  const int cs   = wid & 1;       // gate-col half
  const int lo   = lane & 15;
  const int hi   = lane >> 4;
  const int blk  = blockIdx.x;
  const int L    = blk >> 2;
  const int g    = blk & 3;
  const int KIN  = (L == 0) ? 128 : 64;
  const int NKC  = KIN >> 5;
  const int RM   = R - 1;         // R is a power of two
  const int RC   = (R / CH) > 0 ? (R / CH) : 1;  // ring slack in chunks
  const int NCH  = 512 / CH;

  __shared__ __align__(16) u16 hb[2][32 * 72];
  __shared__ __align__(16) u16 xst[2][32 * 72];
  __shared__ int s_cnt;
  if (tid == 0) s_cnt = 0;
  for (int i = tid; i < 2 * 32 * 72; i += 256) (&hb[0][0])[i] = 0;
  for (int i = tid; i < 2 * 32 * 72; i += 256) (&xst[0][0])[i] = 0;
  __syncthreads();
  {  // dtype probe: even u16s of enc_bih (12288 elems either way)
    u16 v = ((const u16*)ebih_)[2 * tid];
    int e = (v >> 7) & 0xFF;
    if (e >= 100 && e <= 126) atomicAdd(&s_cnt, 1);
  }
  __syncthreads();
  const bool bf = (s_cnt >= 128);   // true: tensors are bf16; false: fp32

  auto ld8 = [&](const void* p, int idx) -> short8 {   // 8 elems -> bf16 frag
    if (bf) return *(const short8*)((const u16*)p + idx);
    const float* f = (const float*)p + idx;
    short8 r;
#pragma unroll
    for (int j = 0; j < 8; ++j) r[j] = (short)f2bf(f[j]);
    return r;
  };
  auto ld1 = [&](const void* p, int idx) -> float {
    return bf ? bf2f(((const u16*)p)[idx]) : ((const float*)p)[idx];
  };

  int T[6];
  T[0] = 2*cs; T[1] = 2*cs+1; T[2] = 4+2*cs; T[3] = 5+2*cs; T[4] = 8+2*cs; T[5] = 9+2*cs;

  short8 zf8 = {0,0,0,0,0,0,0,0};
  short8 wh[6][2];
  short8 wi[6][4];
  short8 wo[2][2];                 // layer-63 only: Wo B-frags
  float  bov[2] = {0.f, 0.f};
  float brz[4], bin2[2], bhn2[2];
#pragma unroll
  for (int a = 0; a < 6; ++a) { wh[a][0]=zf8; wh[a][1]=zf8;
#pragma unroll
    for (int b = 0; b < 4; ++b) wi[a][b]=zf8; }
  wo[0][0]=wo[0][1]=wo[1][0]=wo[1][1]=zf8;

  auto load_phase = [&](int ph) {
    const void* WH = ph ? dWhh_ : eWhh_;
    const void* WI = (L == 0) ? (ph ? dWih0_ : eWih0_) : (ph ? dWih_ : eWih_);
    const int  wbase = L * 192 * 64;
    const int  ibase = (L == 0) ? 0 : (L - 1) * 192 * 64;
    const void* bi = ph ? dbih_ : ebih_;
    const void* bh = ph ? dbhh_ : ebhh_;
#pragma unroll
    for (int ti = 0; ti < 6; ++ti) {
#pragma unroll
      for (int kc = 0; kc < 2; ++kc)
        wh[ti][kc] = ld8(WH, wbase + (T[ti]*16 + lo)*64 + kc*32 + hi*8);
#pragma unroll
      for (int kc = 0; kc < 4; ++kc)
        if (kc < NKC)
          wi[ti][kc] = ld8(WI, ibase + (T[ti]*16 + lo)*KIN + kc*32 + hi*8);
    }
#pragma unroll
    for (int q = 0; q < 4; ++q)
      brz[q] = ld1(bi, L*192 + T[q]*16 + lo) + ld1(bh, L*192 + T[q]*16 + lo);
#pragma unroll
    for (int q = 0; q < 2; ++q) {
      bin2[q] = ld1(bi, L*192 + T[4+q]*16 + lo);
      bhn2[q] = ld1(bh, L*192 + T[4+q]*16 + lo);
    }
  };
  load_phase(0);
  if (L == 63) {
#pragma unroll
    for (int ct = 0; ct < 2; ++ct) {
      int n = 32*wid + 16*ct + lo;
#pragma unroll
      for (int kc = 0; kc < 2; ++kc)
        wo[ct][kc] = ld8(Wo_, n*64 + kc*32 + hi*8);
      bov[ct] = ld1(bo_, n);
    }
  }

  // layer-63 projection of step tprev from full-h LDS buffer hs
  auto do_proj = [&](int tprev, const u16* hs) {
    f32x4 pacc[2][2];
#pragma unroll
    for (int rtl = 0; rtl < 2; ++rtl)
#pragma unroll
      for (int ct = 0; ct < 2; ++ct) {
        float v = bov[ct]; f32x4 tv = {v, v, v, v}; pacc[rtl][ct] = tv;
      }
#pragma unroll
    for (int kc = 0; kc < 2; ++kc) {
      short8 hA0 = *(const short8*)(hs + (0*16 + lo)*72 + kc*32 + hi*8);
      short8 hA1 = *(const short8*)(hs + (1*16 + lo)*72 + kc*32 + hi*8);
      pacc[0][0] = __builtin_amdgcn_mfma_f32_16x16x32_bf16(hA0, wo[0][kc], pacc[0][0], 0, 0, 0);
      pacc[0][1] = __builtin_amdgcn_mfma_f32_16x16x32_bf16(hA0, wo[1][kc], pacc[0][1], 0, 0, 0);
      pacc[1][0] = __builtin_amdgcn_mfma_f32_16x16x32_bf16(hA1, wo[0][kc], pacc[1][0], 0, 0, 0);
      pacc[1][1] = __builtin_amdgcn_mfma_f32_16x16x32_bf16(hA1, wo[1][kc], pacc[1][1], 0, 0, 0);
    }
#pragma unroll
    for (int rtl = 0; rtl < 2; ++rtl)
#pragma unroll
      for (int ct = 0; ct < 2; ++ct) {
        int n = 32*wid + 16*ct + lo;
#pragma unroll
        for (int p = 0; p < 4; ++p) {
          int b = 32*g + rtl*16 + hi*4 + p;
          size_t idx = ((size_t)b * 256 + (tprev - 256)) * 128 + n;
          float v = fminf(64.f, fmaxf(-64.f, pacc[rtl][ct][p]));
          if (bf) ((u16*)out_)[idx] = f2bf(v);
          else    ((float*)out_)[idx] = v;
        }
      }
  };

  float hprev[2][4];
#pragma unroll
  for (int q = 0; q < 2; ++q)
#pragma unroll
    for (int p = 0; p < 4; ++p) hprev[q][p] = 0.f;

  short8 xf[4] = {zf8, zf8, zf8, zf8};
  const int brow = 32*g + rt*16 + lo;
  if (L == 0) {
#pragma unroll
    for (int kc = 0; kc < 4; ++kc)
      xf[kc] = ld8(ctx_, (brow * 256 + 0) * 128 + kc*32 + hi*8);
  }

  const int eIn  = (L > 0 ? L - 1 : 0) * 4 + g;   // deref'd only when L>0
  const int eOut = (L < 63 ? L : 62) * 4 + g;     // deref'd only when L<63
  const u64* recin  = xbuf + (size_t)eIn  * R * 512;
  u64*       recout = xbuf + (size_t)eOut * R * 512;
  int* fin   = pflag + eIn  * FSTRIDE;            // 256B-exclusive per edge
  int* fout  = pflag + eOut * FSTRIDE;
  int* cself = cflag + (L * 4 + g) * FSTRIDE;
  int* cnext = cflag + ((L < 63 ? L + 1 : 63) * 4 + g) * FSTRIDE;

  int budget = 1 << 22;   // anti-hang: waits degrade to no-ops if exhausted

  // stage scatter coords (record layout, verified R3-R6)
  const int srow = (tid >> 7) * 16 + ((tid >> 4) & 3) * 4;
  const int scol = ((tid >> 6) & 1) * 32 + (tid & 15);

  __syncthreads();

  for (int k = 0; k < NCH; ++k) {
    const int t0 = k * CH;
    if (t0 == 256) load_phase(1);

    // ---- once-per-chunk sync: wave 0 / lanes 0-3 poll RELAXED; one acquire
    // re-load on success provides the ordering (same-location monotonicity).
    if (wid == 0) {
      if (L < 63 && k >= RC) {   // ring backpressure (chunk units)
        while (budget > 0) {
          int v = (lane < 4) ? __hip_atomic_load(cnext + lane, __ATOMIC_RELAXED, SCOPE)
                             : 0x7fffffff;
          if (__all(v >= k + 1 - RC)) break;
          --budget; __builtin_amdgcn_s_sleep(2);
        }
        if (lane < 4) (void)__hip_atomic_load(cnext + lane, __ATOMIC_ACQUIRE, SCOPE);
      }
      if (L > 0) {               // producer published chunk k
        while (budget > 0) {
          int v = (lane < 4) ? __hip_atomic_load(fin + lane, __ATOMIC_RELAXED, SCOPE)
                             : 0x7fffffff;
          if (__all(v >= k + 1)) break;
          --budget; __builtin_amdgcn_s_sleep(2);
        }
        if (lane < 4) (void)__hip_atomic_load(fin + lane, __ATOMIC_ACQUIRE, SCOPE);
      }
    }
    __syncthreads();   // Bc: chunk-k records visible; once per chunk

    // ---- prime distance-2 record prefetch
    u64 p0a = 0, p0b = 0, p1a = 0, p1b = 0;
    if (L > 0) {
      const u64* r0 = recin + (size_t)(t0 & RM) * 512 + tid * 2;
      p0a = __hip_atomic_load(r0,     __ATOMIC_RELAXED, SCOPE);
      p0b = __hip_atomic_load(r0 + 1, __ATOMIC_RELAXED, SCOPE);
      if (CH > 1) {
        const u64* r1 = recin + (size_t)((t0 + 1) & RM) * 512 + tid * 2;
        p1a = __hip_atomic_load(r1,     __ATOMIC_RELAXED, SCOPE);
        p1b = __hip_atomic_load(r1 + 1, __ATOMIC_RELAXED, SCOPE);
      }
    }

    for (int tt = 0; tt < CH; ++tt) {
      const int t = t0 + tt;

      // ---- stage x_t (prefetched ~2 steps ago) -> xst[t&1]; refill prefetch reg
      if (L > 0) {
        u64 a = (tt & 1) ? p1a : p0a;
        u64 b = (tt & 1) ? p1b : p0b;
        u16* xd = xst[t & 1];
#pragma unroll
        for (int p = 0; p < 4; ++p) {
          xd[(srow + p) * 72 + scol]      = (u16)(a >> (16 * p));
          xd[(srow + p) * 72 + scol + 16] = (u16)(b >> (16 * p));
        }
        if (tt + 2 < CH) {
          const u64* rn = recin + (size_t)((t + 2) & RM) * 512 + tid * 2;
          u64 na = __hip_atomic_load(rn,     __ATOMIC_RELAXED, SCOPE);
          u64 nb = __hip_atomic_load(rn + 1, __ATOMIC_RELAXED, SCOPE);
          if (tt & 1) { p1a = na; p1b = nb; } else { p0a = na; p0b = nb; }
        }
      }

      lds_barrier();   // B1: xst(t) + hb(t-1) writes visible; NO vmcnt drain

      // ---- layer 63: projection of step t-1 (h_{t-1} lives in hb[(t+1)&1])
      if (L == 63 && t >= 257) do_proj(t - 1, hb[(t + 1) & 1]);

      // ---- accumulators seeded with biases
      f32x4 acc_rz[4], acc_in[2], acc_hn[2];
#pragma unroll
      for (int q = 0; q < 4; ++q) { float v = brz[q];  f32x4 tv = {v, v, v, v}; acc_rz[q] = tv; }
#pragma unroll
      for (int q = 0; q < 2; ++q) { float v = bin2[q]; f32x4 tv = {v, v, v, v}; acc_in[q] = tv;
                                    float w = bhn2[q]; f32x4 tw = {w, w, w, w}; acc_hn[q] = tw; }

      // ---- gh = h_{t-1} @ Whh^T
      const u16* hsrc = hb[(t + 1) & 1];
#pragma unroll
      for (int kc = 0; kc < 2; ++kc) {
        short8 hA = *(const short8*)(hsrc + (rt*16 + lo)*72 + kc*32 + hi*8);
        acc_rz[0] = __builtin_amdgcn_mfma_f32_16x16x32_bf16(hA, wh[0][kc], acc_rz[0], 0, 0, 0);
        acc_rz[1] = __builtin_amdgcn_mfma_f32_16x16x32_bf16(hA, wh[1][kc], acc_rz[1], 0, 0, 0);
        acc_rz[2] = __builtin_amdgcn_mfma_f32_16x16x32_bf16(hA, wh[2][kc], acc_rz[2], 0, 0, 0);
        acc_rz[3] = __builtin_amdgcn_mfma_f32_16x16x32_bf16(hA, wh[3][kc], acc_rz[3], 0, 0, 0);
        acc_hn[0] = __builtin_amdgcn_mfma_f32_16x16x32_bf16(hA, wh[4][kc], acc_hn[0], 0, 0, 0);
        acc_hn[1] = __builtin_amdgcn_mfma_f32_16x16x32_bf16(hA, wh[5][kc], acc_hn[1], 0, 0, 0);
      }

      // ---- x A-frags
      if (L > 0) {
        const u16* xs = xst[t & 1];
#pragma unroll
        for (int kc = 0; kc < 2; ++kc)
          xf[kc] = *(const short8*)(xs + (rt*16 + lo)*72 + kc*32 + hi*8);
      }

      // ---- gi = x_t @ Wih^T  (dec_in[:,0] == 0 -> skip at t==256 for layer 0)
      if (!(L == 0 && t == 256)) {
#pragma unroll
        for (int kc = 0; kc < 4; ++kc) {
          if (kc < NKC) {
            acc_rz[0] = __builtin_amdgcn_mfma_f32_16x16x32_bf16(xf[kc], wi[0][kc], acc_rz[0], 0, 0, 0);
            acc_rz[1] = __builtin_amdgcn_mfma_f32_16x16x32_bf16(xf[kc], wi[1][kc], acc_rz[1], 0, 0, 0);
            acc_rz[2] = __builtin_amdgcn_mfma_f32_16x16x32_bf16(xf[kc], wi[2][kc], acc_rz[2], 0, 0, 0);
            acc_rz[3] = __builtin_amdgcn_mfma_f32_16x16x32_bf16(xf[kc], wi[3][kc], acc_rz[3], 0, 0, 0);
            acc_in[0] = __builtin_amdgcn_mfma_f32_16x16x32_bf16(xf[kc], wi[4][kc], acc_in[0], 0, 0, 0);
            acc_in[1] = __builtin_amdgcn_mfma_f32_16x16x32_bf16(xf[kc], wi[5][kc], acc_in[1], 0, 0, 0);
          }
        }
      }

      // ---- layer 0: prefetch x for t+1 (floats across the raw barrier)
      if (L == 0) {
        int tn = t + 1;
        int tx = (tn < 256) ? tn : ((tn == 256) ? 0 : tn - 257);
#pragma unroll
        for (int kc = 0; kc < 4; ++kc)
          xf[kc] = ld8(ctx_, (brow * 256 + tx) * 128 + kc*32 + hi*8);
      }

      // ---- gates (fp32; reg p -> batch row hi*4+p). |h|<=1 invariant; clamp = no-op guard
      u16 hbits[2][4];
#pragma unroll
      for (int q = 0; q < 2; ++q) {
#pragma unroll
        for (int p = 0; p < 4; ++p) {
          float r = sigm(acc_rz[q][p]);
          float z = sigm(acc_rz[2 + q][p]);
          float n = tanhf_(acc_in[q][p] + r * acc_hn[q][p]);
          float h = n + z * (hprev[q][p] - n);
          h = fminf(1.f, fmaxf(-1.f, h));
          hprev[q][p] = h;
          hbits[q][p] = f2bf(h);
        }
      }

      // ---- h_t -> LDS (visible after next step's B1)
      u16* hd = hb[t & 1];
#pragma unroll
      for (int q = 0; q < 2; ++q)
#pragma unroll
        for (int p = 0; p < 4; ++p)
          hd[(rt*16 + hi*4 + p) * 72 + cs*32 + q*16 + lo] = hbits[q][p];

      // ---- stream h_t record (relaxed; drained once per chunk by the release)
      if (L < 63) {
        u64 da = (u64)hbits[0][0] | ((u64)hbits[0][1] << 16) | ((u64)hbits[0][2] << 32) | ((u64)hbits[0][3] << 48);
        u64 db = (u64)hbits[1][0] | ((u64)hbits[1][1] << 16) | ((u64)hbits[1][2] << 32) | ((u64)hbits[1][3] << 48);
        u64* ro = recout + (size_t)(t & RM) * 512 + tid * 2;
        __hip_atomic_store(ro,     da, __ATOMIC_RELAXED, SCOPE);
        __hip_atomic_store(ro + 1, db, __ATOMIC_RELAXED, SCOPE);
      }
    }

    // ---- once-per-chunk publication (per-WAVE release, vmcnt drain amortized)
    if (L < 63 && lane == 0)
      __hip_atomic_store(fout + wid, k + 1, __ATOMIC_RELEASE, SCOPE);
    if (L > 0 && lane == 0)
      __hip_atomic_store(cself + wid, k + 1, __ATOMIC_RELEASE, SCOPE);
  }

  // ---- epilogue: projection of the final step (t = 511)
  lds_barrier();
  if (L == 63) do_proj(511, hb[1]);
}

extern "C" void kernel_launch(void* const* d_in, const int* in_sizes, int n_in,
                              void* d_out, int out_size, void* d_ws, size_t ws_size,
                              hipStream_t stream)
{
  char* ws = (char*)d_ws;
  int* pflag = (int*)ws;                    // 64KB: per-edge 256B flag lines
  int* cflag = (int*)(ws + 65536);          // 64KB
  u64* xbuf  = (u64*)(ws + 262144);         // handoff ring

  size_t avail = (ws_size > 262144) ? ws_size - 262144 : 0;
  size_t per_slot = (size_t)63 * 4 * 4096;  // one ring step across all (l,g) edges
  int R = 1;
  for (int r = 128; r >= 1; r >>= 1)
    if ((size_t)r * per_slot <= avail) { R = r; break; }
  int CH = (R >= 8) ? 4 : ((R >= 2) ? R / 2 : 1);   // CH | 256 guaranteed

  hipMemsetAsync(ws, 0, 262144, stream);    // zero flags every launch
  gru_pipeline<<<256, 256, 0, stream>>>(
      d_in[0], d_in[1], d_in[2], d_in[3], d_in[4], d_in[5],
      d_in[6], d_in[7], d_in[8], d_in[9], d_in[10], d_in[11], d_in[12],
      d_out, pflag, cflag, xbuf, R, CH);
  (void)in_sizes; (void)n_in; (void)out_size;
}

// Round 8
// 4757.310 us; speedup vs baseline: 4.0894x; 1.0242x over previous
//
#include <hip/hip_runtime.h>
#include <stdint.h>

typedef uint16_t u16;
typedef unsigned long long u64;
typedef __attribute__((ext_vector_type(8))) short short8;   // 8 x bf16 bits (4 VGPRs)
typedef __attribute__((ext_vector_type(4))) float f32x4;

#define SCOPE __HIP_MEMORY_SCOPE_AGENT
#define FSTRIDE 64   // ints per edge flag line (256B, exclusive per edge)

static __device__ __forceinline__ float bf2f(u16 b) {
  union { uint32_t u; float f; } x; x.u = ((uint32_t)b) << 16; return x.f;
}
static __device__ __forceinline__ u16 f2bf(float f) {
  union { float f; uint32_t u; } x; x.f = f;
  uint32_t u = x.u;
  u += 0x7fffu + ((u >> 16) & 1u);   // RTNE
  return (u16)(u >> 16);
}
static __device__ __forceinline__ float sigm(float x) {
  x = fminf(30.f, fmaxf(-30.f, x));
  return __builtin_amdgcn_rcpf(1.f + __expf(-x));
}
static __device__ __forceinline__ float tanhf_(float x) {
  x = fminf(15.f, fmaxf(-15.f, x));
  return 1.f - 2.f * __builtin_amdgcn_rcpf(1.f + __expf(2.f * x));
}
// LDS-only barrier: does NOT drain vmcnt.
static __device__ __forceinline__ void lds_barrier() {
  asm volatile("s_waitcnt lgkmcnt(0)\n\ts_barrier" ::: "memory");
}

// Persistent pipelined GRU. One WG per (layer L, batch chunk g of 32 rows).
// R8 insight (fit of R5-R7: c~5.4us/step, D~4us): vmcnt is ONE in-order counter
// per wave — loads issued after record stores must drain the stores' MALL acks
// before their own s_waitcnt can pass, so any rolling prefetch is nullified.
// Fix: at chunk start, issue ALL CH steps' loads (records -> pra/prb regs for
// L>0; ctx -> cxf regs for L==0) BEFORE any in-chunk store. Ops issued after a
// load never delay it => steps are vm-wait-free; stores retire during the next
// chunk's poll. 1 wave/SIMD regardless of VGPR (256 WGs x 4 waves), so the
// prime arrays are free.
// MFMA 16x16x32 bf16 layouts (m89-verified):
//   A: lane holds A[m=lane&15][k=(lane>>4)*8 + j]
//   B: lane holds B[k=(lane>>4)*8 + j][n=lane&15]
//   C/D: reg p -> (row=(lane>>4)*4+p, col=lane&15)
template <int CH>
__global__ __launch_bounds__(256, 1) void gru_pipeline(
    const void* ctx_,
    const void* eWih0_, const void* eWih_, const void* eWhh_,
    const void* ebih_,  const void* ebhh_,
    const void* dWih0_, const void* dWih_, const void* dWhh_,
    const void* dbih_,  const void* dbhh_,
    const void* Wo_,    const void* bo_,   void* out_,
    int* __restrict__ pflag, int* __restrict__ cflag,
    u64* __restrict__ xbuf, int R)
{
  const int tid  = threadIdx.x;
  const int lane = tid & 63;
  const int wid  = tid >> 6;
  const int rt   = wid >> 1;      // row-tile (16 batch rows each)
  const int cs   = wid & 1;       // gate-col half
  const int lo   = lane & 15;
  const int hi   = lane >> 4;
  const int blk  = blockIdx.x;
  const int L    = blk >> 2;
  const int g    = blk & 3;
  const int KIN  = (L == 0) ? 128 : 64;
  const int NKC  = KIN >> 5;
  const int RM   = R - 1;         // R is a power of two
  const int RC   = (R / CH) > 0 ? (R / CH) : 1;  // ring slack in chunks
  const int NCH  = 512 / CH;

  __shared__ __align__(16) u16 hb[2][32 * 72];
  __shared__ __align__(16) u16 xst[2][32 * 72];
  __shared__ int s_cnt;
  if (tid == 0) s_cnt = 0;
  for (int i = tid; i < 2 * 32 * 72; i += 256) (&hb[0][0])[i] = 0;
  for (int i = tid; i < 2 * 32 * 72; i += 256) (&xst[0][0])[i] = 0;
  __syncthreads();
  {  // dtype probe: even u16s of enc_bih
    u16 v = ((const u16*)ebih_)[2 * tid];
    int e = (v >> 7) & 0xFF;
    if (e >= 100 && e <= 126) atomicAdd(&s_cnt, 1);
  }
  __syncthreads();
  const bool bf = (s_cnt >= 128);   // true: tensors are bf16; false: fp32

  auto ld8 = [&](const void* p, int idx) -> short8 {
    if (bf) return *(const short8*)((const u16*)p + idx);
    const float* f = (const float*)p + idx;
    short8 r;
#pragma unroll
    for (int j = 0; j < 8; ++j) r[j] = (short)f2bf(f[j]);
    return r;
  };
  auto ld1 = [&](const void* p, int idx) -> float {
    return bf ? bf2f(((const u16*)p)[idx]) : ((const float*)p)[idx];
  };

  int T[6];
  T[0] = 2*cs; T[1] = 2*cs+1; T[2] = 4+2*cs; T[3] = 5+2*cs; T[4] = 8+2*cs; T[5] = 9+2*cs;

  short8 zf8 = {0,0,0,0,0,0,0,0};
  short8 wh[6][2];
  short8 wi[6][4];
  short8 wo[2][2];
  float  bov[2] = {0.f, 0.f};
  float brz[4], bin2[2], bhn2[2];
#pragma unroll
  for (int a = 0; a < 6; ++a) { wh[a][0]=zf8; wh[a][1]=zf8;
#pragma unroll
    for (int b = 0; b < 4; ++b) wi[a][b]=zf8; }
  wo[0][0]=wo[0][1]=wo[1][0]=wo[1][1]=zf8;

  auto load_phase = [&](int ph) {
    const void* WH = ph ? dWhh_ : eWhh_;
    const void* WI = (L == 0) ? (ph ? dWih0_ : eWih0_) : (ph ? dWih_ : eWih_);
    const int  wbase = L * 192 * 64;
    const int  ibase = (L == 0) ? 0 : (L - 1) * 192 * 64;
    const void* bi = ph ? dbih_ : ebih_;
    const void* bh = ph ? dbhh_ : ebhh_;
#pragma unroll
    for (int ti = 0; ti < 6; ++ti) {
#pragma unroll
      for (int kc = 0; kc < 2; ++kc)
        wh[ti][kc] = ld8(WH, wbase + (T[ti]*16 + lo)*64 + kc*32 + hi*8);
#pragma unroll
      for (int kc = 0; kc < 4; ++kc)
        if (kc < NKC)
          wi[ti][kc] = ld8(WI, ibase + (T[ti]*16 + lo)*KIN + kc*32 + hi*8);
    }
#pragma unroll
    for (int q = 0; q < 4; ++q)
      brz[q] = ld1(bi, L*192 + T[q]*16 + lo) + ld1(bh, L*192 + T[q]*16 + lo);
#pragma unroll
    for (int q = 0; q < 2; ++q) {
      bin2[q] = ld1(bi, L*192 + T[4+q]*16 + lo);
      bhn2[q] = ld1(bh, L*192 + T[4+q]*16 + lo);
    }
  };
  load_phase(0);
  if (L == 63) {
#pragma unroll
    for (int ct = 0; ct < 2; ++ct) {
      int n = 32*wid + 16*ct + lo;
#pragma unroll
      for (int kc = 0; kc < 2; ++kc)
        wo[ct][kc] = ld8(Wo_, n*64 + kc*32 + hi*8);
      bov[ct] = ld1(bo_, n);
    }
  }

  auto do_proj = [&](int tprev, const u16* hs) {
    f32x4 pacc[2][2];
#pragma unroll
    for (int rtl = 0; rtl < 2; ++rtl)
#pragma unroll
      for (int ct = 0; ct < 2; ++ct) {
        float v = bov[ct]; f32x4 tv = {v, v, v, v}; pacc[rtl][ct] = tv;
      }
#pragma unroll
    for (int kc = 0; kc < 2; ++kc) {
      short8 hA0 = *(const short8*)(hs + (0*16 + lo)*72 + kc*32 + hi*8);
      short8 hA1 = *(const short8*)(hs + (1*16 + lo)*72 + kc*32 + hi*8);
      pacc[0][0] = __builtin_amdgcn_mfma_f32_16x16x32_bf16(hA0, wo[0][kc], pacc[0][0], 0, 0, 0);
      pacc[0][1] = __builtin_amdgcn_mfma_f32_16x16x32_bf16(hA0, wo[1][kc], pacc[0][1], 0, 0, 0);
      pacc[1][0] = __builtin_amdgcn_mfma_f32_16x16x32_bf16(hA1, wo[0][kc], pacc[1][0], 0, 0, 0);
      pacc[1][1] = __builtin_amdgcn_mfma_f32_16x16x32_bf16(hA1, wo[1][kc], pacc[1][1], 0, 0, 0);
    }
#pragma unroll
    for (int rtl = 0; rtl < 2; ++rtl)
#pragma unroll
      for (int ct = 0; ct < 2; ++ct) {
        int n = 32*wid + 16*ct + lo;
#pragma unroll
        for (int p = 0; p < 4; ++p) {
          int b = 32*g + rtl*16 + hi*4 + p;
          size_t idx = ((size_t)b * 256 + (tprev - 256)) * 128 + n;
          float v = fminf(64.f, fmaxf(-64.f, pacc[rtl][ct][p]));
          if (bf) ((u16*)out_)[idx] = f2bf(v);
          else    ((float*)out_)[idx] = v;
        }
      }
  };

  float hprev[2][4];
#pragma unroll
  for (int q = 0; q < 2; ++q)
#pragma unroll
    for (int p = 0; p < 4; ++p) hprev[q][p] = 0.f;

  const int brow = 32*g + rt*16 + lo;

  const int eIn  = (L > 0 ? L - 1 : 0) * 4 + g;
  const int eOut = (L < 63 ? L : 62) * 4 + g;
  const u64* recin  = xbuf + (size_t)eIn  * R * 512;
  u64*       recout = xbuf + (size_t)eOut * R * 512;
  int* fin   = pflag + eIn  * FSTRIDE;
  int* fout  = pflag + eOut * FSTRIDE;
  int* cself = cflag + (L * 4 + g) * FSTRIDE;
  int* cnext = cflag + ((L < 63 ? L + 1 : 63) * 4 + g) * FSTRIDE;

  int budget = 1 << 22;   // anti-hang

  const int srow = (tid >> 7) * 16 + ((tid >> 4) & 3) * 4;
  const int scol = ((tid >> 6) & 1) * 32 + (tid & 15);

  __syncthreads();

  for (int k = 0; k < NCH; ++k) {
    const int t0 = k * CH;
    if (t0 == 256) load_phase(1);

    // ---- once-per-chunk sync: wave 0 / lanes 0-3 poll relaxed; one acquire
    if (wid == 0) {
      if (L < 63 && k >= RC) {
        while (budget > 0) {
          int v = (lane < 4) ? __hip_atomic_load(cnext + lane, __ATOMIC_RELAXED, SCOPE)
                             : 0x7fffffff;
          if (__all(v >= k + 1 - RC)) break;
          --budget; __builtin_amdgcn_s_sleep(2);
        }
        if (lane < 4) (void)__hip_atomic_load(cnext + lane, __ATOMIC_ACQUIRE, SCOPE);
      }
      if (L > 0) {
        while (budget > 0) {
          int v = (lane < 4) ? __hip_atomic_load(fin + lane, __ATOMIC_RELAXED, SCOPE)
                             : 0x7fffffff;
          if (__all(v >= k + 1)) break;
          --budget; __builtin_amdgcn_s_sleep(2);
        }
        if (lane < 4) (void)__hip_atomic_load(fin + lane, __ATOMIC_ACQUIRE, SCOPE);
      }
    }
    __syncthreads();   // Bc: chunk-k records visible; drains prev chunk (mostly retired)

    // ---- PRIME: issue the whole chunk's loads BEFORE any in-chunk store.
    u64   pra[CH], prb[CH];        // L>0: record frags
    short8 cxf[CH][4];             // L==0: ctx A-frags
    if (L > 0) {
#pragma unroll
      for (int j = 0; j < CH; ++j) {
        const u64* rj = recin + (size_t)((t0 + j) & RM) * 512 + tid * 2;
        pra[j] = __hip_atomic_load(rj,     __ATOMIC_RELAXED, SCOPE);
        prb[j] = __hip_atomic_load(rj + 1, __ATOMIC_RELAXED, SCOPE);
      }
    } else {
#pragma unroll
      for (int j = 0; j < CH; ++j) {
        int t = t0 + j;
        int tx = (t < 256) ? t : ((t == 256) ? 0 : t - 257);
#pragma unroll
        for (int kc = 0; kc < 4; ++kc)
          cxf[j][kc] = ld8(ctx_, (brow * 256 + tx) * 128 + kc*32 + hi*8);
      }
    }
    asm volatile("" ::: "memory");   // pin: loads above stay above the stores below

#pragma unroll 1
    for (int tt = 0; tt < CH; ++tt) {
      const int t = t0 + tt;

      // ---- stage x_t (primed regs) -> xst[t&1]
      if (L > 0) {
        u16* xd = xst[t & 1];
#pragma unroll
        for (int p = 0; p < 4; ++p) {
          xd[(srow + p) * 72 + scol]      = (u16)(pra[tt] >> (16 * p));
          xd[(srow + p) * 72 + scol + 16] = (u16)(prb[tt] >> (16 * p));
        }
      }

      lds_barrier();   // B1: xst(t) + hb(t-1) writes visible; NO vmcnt drain

      // ---- layer 63: projection of step t-1 (h_{t-1} in hb[(t+1)&1])
      if (L == 63 && t >= 257) do_proj(t - 1, hb[(t + 1) & 1]);

      // ---- accumulators seeded with biases
      f32x4 acc_rz[4], acc_in[2], acc_hn[2];
#pragma unroll
      for (int q = 0; q < 4; ++q) { float v = brz[q];  f32x4 tv = {v, v, v, v}; acc_rz[q] = tv; }
#pragma unroll
      for (int q = 0; q < 2; ++q) { float v = bin2[q]; f32x4 tv = {v, v, v, v}; acc_in[q] = tv;
                                    float w = bhn2[q]; f32x4 tw = {w, w, w, w}; acc_hn[q] = tw; }

      // ---- gh = h_{t-1} @ Whh^T
      const u16* hsrc = hb[(t + 1) & 1];
#pragma unroll
      for (int kc = 0; kc < 2; ++kc) {
        short8 hA = *(const short8*)(hsrc + (rt*16 + lo)*72 + kc*32 + hi*8);
        acc_rz[0] = __builtin_amdgcn_mfma_f32_16x16x32_bf16(hA, wh[0][kc], acc_rz[0], 0, 0, 0);
        acc_rz[1] = __builtin_amdgcn_mfma_f32_16x16x32_bf16(hA, wh[1][kc], acc_rz[1], 0, 0, 0);
        acc_rz[2] = __builtin_amdgcn_mfma_f32_16x16x32_bf16(hA, wh[2][kc], acc_rz[2], 0, 0, 0);
        acc_rz[3] = __builtin_amdgcn_mfma_f32_16x16x32_bf16(hA, wh[3][kc], acc_rz[3], 0, 0, 0);
        acc_hn[0] = __builtin_amdgcn_mfma_f32_16x16x32_bf16(hA, wh[4][kc], acc_hn[0], 0, 0, 0);
        acc_hn[1] = __builtin_amdgcn_mfma_f32_16x16x32_bf16(hA, wh[5][kc], acc_hn[1], 0, 0, 0);
      }

      // ---- x A-frags
      short8 xf[4] = {zf8, zf8, zf8, zf8};
      if (L > 0) {
        const u16* xs = xst[t & 1];
#pragma unroll
        for (int kc = 0; kc < 2; ++kc)
          xf[kc] = *(const short8*)(xs + (rt*16 + lo)*72 + kc*32 + hi*8);
      } else {
#pragma unroll
        for (int kc = 0; kc < 4; ++kc) xf[kc] = cxf[tt][kc];
      }

      // ---- gi = x_t @ Wih^T  (dec_in[:,0] == 0 -> skip at t==256 for layer 0)
      if (!(L == 0 && t == 256)) {
#pragma unroll
        for (int kc = 0; kc < 4; ++kc) {
          if (kc < NKC) {
            acc_rz[0] = __builtin_amdgcn_mfma_f32_16x16x32_bf16(xf[kc], wi[0][kc], acc_rz[0], 0, 0, 0);
            acc_rz[1] = __builtin_amdgcn_mfma_f32_16x16x32_bf16(xf[kc], wi[1][kc], acc_rz[1], 0, 0, 0);
            acc_rz[2] = __builtin_amdgcn_mfma_f32_16x16x32_bf16(xf[kc], wi[2][kc], acc_rz[2], 0, 0, 0);
            acc_rz[3] = __builtin_amdgcn_mfma_f32_16x16x32_bf16(xf[kc], wi[3][kc], acc_rz[3], 0, 0, 0);
            acc_in[0] = __builtin_amdgcn_mfma_f32_16x16x32_bf16(xf[kc], wi[4][kc], acc_in[0], 0, 0, 0);
            acc_in[1] = __builtin_amdgcn_mfma_f32_16x16x32_bf16(xf[kc], wi[5][kc], acc_in[1], 0, 0, 0);
          }
        }
      }

      // ---- gates
      u16 hbits[2][4];
#pragma unroll
      for (int q = 0; q < 2; ++q) {
#pragma unroll
        for (int p = 0; p < 4; ++p) {
          float r = sigm(acc_rz[q][p]);
          float z = sigm(acc_rz[2 + q][p]);
          float n = tanhf_(acc_in[q][p] + r * acc_hn[q][p]);
          float h = n + z * (hprev[q][p] - n);
          h = fminf(1.f, fmaxf(-1.f, h));
          hprev[q][p] = h;
          hbits[q][p] = f2bf(h);
        }
      }

      // ---- h_t -> LDS
      u16* hd = hb[t & 1];
#pragma unroll
      for (int q = 0; q < 2; ++q)
#pragma unroll
        for (int p = 0; p < 4; ++p)
          hd[(rt*16 + hi*4 + p) * 72 + cs*32 + q*16 + lo] = hbits[q][p];

      // ---- stream h_t record (relaxed; drained by the chunk-end release)
      if (L < 63) {
        u64 da = (u64)hbits[0][0] | ((u64)hbits[0][1] << 16) | ((u64)hbits[0][2] << 32) | ((u64)hbits[0][3] << 48);
        u64 db = (u64)hbits[1][0] | ((u64)hbits[1][1] << 16) | ((u64)hbits[1][2] << 32) | ((u64)hbits[1][3] << 48);
        u64* ro = recout + (size_t)(t & RM) * 512 + tid * 2;
        __hip_atomic_store(ro,     da, __ATOMIC_RELAXED, SCOPE);
        __hip_atomic_store(ro + 1, db, __ATOMIC_RELAXED, SCOPE);
      }
    }

    // ---- once-per-chunk publication (per-WAVE release)
    if (L < 63 && lane == 0)
      __hip_atomic_store(fout + wid, k + 1, __ATOMIC_RELEASE, SCOPE);
    if (L > 0 && lane == 0)
      __hip_atomic_store(cself + wid, k + 1, __ATOMIC_RELEASE, SCOPE);
  }

  // ---- epilogue: projection of the final step (t = 511)
  lds_barrier();
  if (L == 63) do_proj(511, hb[1]);
}

extern "C" void kernel_launch(void* const* d_in, const int* in_sizes, int n_in,
                              void* d_out, int out_size, void* d_ws, size_t ws_size,
                              hipStream_t stream)
{
  char* ws = (char*)d_ws;
  int* pflag = (int*)ws;                    // 64KB: per-edge 256B flag lines
  int* cflag = (int*)(ws + 65536);          // 64KB
  u64* xbuf  = (u64*)(ws + 262144);         // handoff ring

  size_t avail = (ws_size > 262144) ? ws_size - 262144 : 0;
  size_t per_slot = (size_t)63 * 4 * 4096;  // one ring step across all (l,g) edges
  int R = 1;
  for (int r = 64; r >= 1; r >>= 1)
    if ((size_t)r * per_slot <= avail) { R = r; break; }

  hipMemsetAsync(ws, 0, 262144, stream);    // zero flags every launch

#define LAUNCH(CHV)                                                        \
  gru_pipeline<CHV><<<256, 256, 0, stream>>>(                              \
      d_in[0], d_in[1], d_in[2], d_in[3], d_in[4], d_in[5],                \
      d_in[6], d_in[7], d_in[8], d_in[9], d_in[10], d_in[11], d_in[12],    \
      d_out, pflag, cflag, xbuf, R)

  if      (R >= 8) LAUNCH(4);
  else if (R >= 4) LAUNCH(2);
  else             LAUNCH(1);
#undef LAUNCH
  (void)in_sizes; (void)n_in; (void)out_size;
}

// Round 9
// 2754.075 us; speedup vs baseline: 7.0639x; 1.7274x over previous
//
#include <hip/hip_runtime.h>
#include <stdint.h>

typedef uint16_t u16;
typedef unsigned long long u64;
typedef __attribute__((ext_vector_type(8))) short short8;   // 8 x bf16 bits (4 VGPRs)
typedef __attribute__((ext_vector_type(4))) float f32x4;

#define SCOPE __HIP_MEMORY_SCOPE_AGENT
#define FSTRIDE 64   // ints per edge flag line (256B, exclusive per edge)

static __device__ __forceinline__ float bf2f(u16 b) {
  union { uint32_t u; float f; } x; x.u = ((uint32_t)b) << 16; return x.f;
}
static __device__ __forceinline__ u16 f2bf(float f) {
  union { float f; uint32_t u; } x; x.f = f;
  uint32_t u = x.u;
  u += 0x7fffu + ((u >> 16) & 1u);   // RTNE
  return (u16)(u >> 16);
}
static __device__ __forceinline__ float sigm(float x) {
  x = fminf(30.f, fmaxf(-30.f, x));
  return __builtin_amdgcn_rcpf(1.f + __expf(-x));
}
static __device__ __forceinline__ float tanhf_(float x) {
  x = fminf(15.f, fmaxf(-15.f, x));
  return 1.f - 2.f * __builtin_amdgcn_rcpf(1.f + __expf(2.f * x));
}
// LDS-only barrier: does NOT drain vmcnt.
static __device__ __forceinline__ void lds_barrier() {
  asm volatile("s_waitcnt lgkmcnt(0)\n\ts_barrier" ::: "memory");
}

// R9: TWO adjacent layers fused per WG. 128 WGs = 32 pairs x 4 batch-chunks.
// Rationale (fit of R6-R8): duration pinned at hbm_bytes/~300GB/s — the 63-edge
// agent-scope ring (516MB r + 516MB w of sc1 MALL traffic) is the wall, plus
// 63 hops of fill. Fusion halves edges (31), hops (31), and pollers. Intra-pair
// handoff is an LDS round-trip (xstB), zero coherence traffic.
// Flag protocol simplified: chunk-end __syncthreads (drains ALL waves' record
// stores once per chunk) + ONE release flag per edge; consumer wave-0 polls the
// single flag (all lanes same addr -> one request), acquire re-load on success.
// MFMA 16x16x32 bf16 layouts (m89-verified):
//   A-frag: lane holds A[m=lane&15][k=(lane>>4)*8+j]
//   B-frag: lane holds B[k=(lane>>4)*8+j][n=lane&15]  (W row-major (N,K))
//   C/D: reg p -> (row=(lane>>4)*4+p, col=lane&15)
template <int CH>
__global__ __launch_bounds__(256, 1) void gru_pipeline(
    const void* ctx_,
    const void* eWih0_, const void* eWih_, const void* eWhh_,
    const void* ebih_,  const void* ebhh_,
    const void* dWih0_, const void* dWih_, const void* dWhh_,
    const void* dbih_,  const void* dbhh_,
    const void* Wo_,    const void* bo_,   void* out_,
    int* __restrict__ pflag, int* __restrict__ cflag,
    u64* __restrict__ xbuf, int R)
{
  const int tid  = threadIdx.x;
  const int lane = tid & 63;
  const int wid  = tid >> 6;
  const int rt   = wid >> 1;      // row-tile (16 batch rows each)
  const int cs   = wid & 1;       // gate-col half
  const int lo   = lane & 15;
  const int hi   = lane >> 4;
  const int blk  = blockIdx.x;
  const int P    = blk >> 2;      // layer pair 0..31  (layers 2P, 2P+1)
  const int g    = blk & 3;       // batch chunk
  const int LA   = 2 * P;
  const int LB   = 2 * P + 1;
  const int NKCA = (P == 0) ? 4 : 2;   // layer A k-chunks (K=128 for layer 0)
  const int RM   = R - 1;              // R is a power of two
  const int RC   = (R / CH) > 0 ? (R / CH) : 1;
  const int NCH  = 512 / CH;

  __shared__ __align__(16) u16 hbA[2][32 * 72];
  __shared__ __align__(16) u16 hbB[2][32 * 72];
  __shared__ __align__(16) u16 xstA[2][32 * 72];
  __shared__ __align__(16) u16 xstB[32 * 72];
  __shared__ int s_cnt;
  if (tid == 0) s_cnt = 0;
  for (int i = tid; i < 32 * 72; i += 256) {
    hbA[0][i] = 0; hbA[1][i] = 0; hbB[0][i] = 0; hbB[1][i] = 0;
    xstA[0][i] = 0; xstA[1][i] = 0; xstB[i] = 0;
  }
  __syncthreads();
  {  // dtype probe: even u16s of enc_bih
    u16 v = ((const u16*)ebih_)[2 * tid];
    int e = (v >> 7) & 0xFF;
    if (e >= 100 && e <= 126) atomicAdd(&s_cnt, 1);
  }
  __syncthreads();
  const bool bf = (s_cnt >= 128);   // true: bf16 tensors; false: fp32

  auto ld8 = [&](const void* p, int idx) -> short8 {
    if (bf) return *(const short8*)((const u16*)p + idx);
    const float* f = (const float*)p + idx;
    short8 r;
#pragma unroll
    for (int j = 0; j < 8; ++j) r[j] = (short)f2bf(f[j]);
    return r;
  };
  auto ld1 = [&](const void* p, int idx) -> float {
    return bf ? bf2f(((const u16*)p)[idx]) : ((const float*)p)[idx];
  };

  int T[6];
  T[0] = 2*cs; T[1] = 2*cs+1; T[2] = 4+2*cs; T[3] = 5+2*cs; T[4] = 8+2*cs; T[5] = 9+2*cs;

  short8 zf8 = {0,0,0,0,0,0,0,0};
  short8 whA[6][2], wiA[6][4];     // layer A (wiA[.][2..3] only for P==0)
  short8 whB[6][2], wiB[6][2];     // layer B
  short8 wo[2][2];                 // pair-31 only
  float  bov[2] = {0.f, 0.f};
  float brzA[4], binA[2], bhnA[2];
  float brzB[4], binB[2], bhnB[2];
#pragma unroll
  for (int a = 0; a < 6; ++a) {
    whA[a][0]=zf8; whA[a][1]=zf8; whB[a][0]=zf8; whB[a][1]=zf8;
    wiB[a][0]=zf8; wiB[a][1]=zf8;
#pragma unroll
    for (int b = 0; b < 4; ++b) wiA[a][b]=zf8;
  }
  wo[0][0]=wo[0][1]=wo[1][0]=wo[1][1]=zf8;

  auto load_phase = [&](int ph) {
    const void* WH = ph ? dWhh_ : eWhh_;
    const void* WIs = ph ? dWih_ : eWih_;
    const void* WI0 = ph ? dWih0_ : eWih0_;
    const void* bi = ph ? dbih_ : ebih_;
    const void* bh = ph ? dbhh_ : ebhh_;
    const void* WIA = (LA == 0) ? WI0 : WIs;
    const int  iA   = (LA == 0) ? 0 : (LA - 1) * 192 * 64;
    const int  KINA = (LA == 0) ? 128 : 64;
#pragma unroll
    for (int ti = 0; ti < 6; ++ti) {
#pragma unroll
      for (int kc = 0; kc < 2; ++kc) {
        whA[ti][kc] = ld8(WH, LA*192*64 + (T[ti]*16 + lo)*64 + kc*32 + hi*8);
        whB[ti][kc] = ld8(WH, LB*192*64 + (T[ti]*16 + lo)*64 + kc*32 + hi*8);
        wiB[ti][kc] = ld8(WIs, LA*192*64 + (T[ti]*16 + lo)*64 + kc*32 + hi*8); // Wih[LB-1]=Wih[LA]
      }
#pragma unroll
      for (int kc = 0; kc < 4; ++kc)
        if (kc < NKCA)
          wiA[ti][kc] = ld8(WIA, iA + (T[ti]*16 + lo)*KINA + kc*32 + hi*8);
    }
#pragma unroll
    for (int q = 0; q < 4; ++q) {
      brzA[q] = ld1(bi, LA*192 + T[q]*16 + lo) + ld1(bh, LA*192 + T[q]*16 + lo);
      brzB[q] = ld1(bi, LB*192 + T[q]*16 + lo) + ld1(bh, LB*192 + T[q]*16 + lo);
    }
#pragma unroll
    for (int q = 0; q < 2; ++q) {
      binA[q] = ld1(bi, LA*192 + T[4+q]*16 + lo);
      bhnA[q] = ld1(bh, LA*192 + T[4+q]*16 + lo);
      binB[q] = ld1(bi, LB*192 + T[4+q]*16 + lo);
      bhnB[q] = ld1(bh, LB*192 + T[4+q]*16 + lo);
    }
  };
  load_phase(0);
  if (P == 31) {
#pragma unroll
    for (int ct = 0; ct < 2; ++ct) {
      int n = 32*wid + 16*ct + lo;
#pragma unroll
      for (int kc = 0; kc < 2; ++kc)
        wo[ct][kc] = ld8(Wo_, n*64 + kc*32 + hi*8);
      bov[ct] = ld1(bo_, n);
    }
  }

  auto do_proj = [&](int tprev, const u16* hs) {
    f32x4 pacc[2][2];
#pragma unroll
    for (int rtl = 0; rtl < 2; ++rtl)
#pragma unroll
      for (int ct = 0; ct < 2; ++ct) {
        float v = bov[ct]; f32x4 tv = {v, v, v, v}; pacc[rtl][ct] = tv;
      }
#pragma unroll
    for (int kc = 0; kc < 2; ++kc) {
      short8 hA0 = *(const short8*)(hs + (0*16 + lo)*72 + kc*32 + hi*8);
      short8 hA1 = *(const short8*)(hs + (1*16 + lo)*72 + kc*32 + hi*8);
      pacc[0][0] = __builtin_amdgcn_mfma_f32_16x16x32_bf16(hA0, wo[0][kc], pacc[0][0], 0, 0, 0);
      pacc[0][1] = __builtin_amdgcn_mfma_f32_16x16x32_bf16(hA0, wo[1][kc], pacc[0][1], 0, 0, 0);
      pacc[1][0] = __builtin_amdgcn_mfma_f32_16x16x32_bf16(hA1, wo[0][kc], pacc[1][0], 0, 0, 0);
      pacc[1][1] = __builtin_amdgcn_mfma_f32_16x16x32_bf16(hA1, wo[1][kc], pacc[1][1], 0, 0, 0);
    }
#pragma unroll
    for (int rtl = 0; rtl < 2; ++rtl)
#pragma unroll
      for (int ct = 0; ct < 2; ++ct) {
        int n = 32*wid + 16*ct + lo;
#pragma unroll
        for (int p = 0; p < 4; ++p) {
          int b = 32*g + rtl*16 + hi*4 + p;
          size_t idx = ((size_t)b * 256 + (tprev - 256)) * 128 + n;
          float v = fminf(64.f, fmaxf(-64.f, pacc[rtl][ct][p]));
          if (bf) ((u16*)out_)[idx] = f2bf(v);
          else    ((float*)out_)[idx] = v;
        }
      }
  };

  float hprevA[2][4], hprevB[2][4];
#pragma unroll
  for (int q = 0; q < 2; ++q)
#pragma unroll
    for (int p = 0; p < 4; ++p) { hprevA[q][p] = 0.f; hprevB[q][p] = 0.f; }

  const int brow = 32*g + rt*16 + lo;

  const int eIn  = (P > 0 ? P - 1 : 0) * 4 + g;   // deref'd only when P>0
  const int eOut = (P < 31 ? P : 30) * 4 + g;     // deref'd only when P<31
  const u64* recin  = xbuf + (size_t)eIn  * R * 512;
  u64*       recout = xbuf + (size_t)eOut * R * 512;
  int* fin   = pflag + eIn  * FSTRIDE;            // single flag per edge
  int* fout  = pflag + eOut * FSTRIDE;
  int* cself = cflag + (P * 4 + g) * FSTRIDE;
  int* cnext = cflag + ((P < 31 ? P + 1 : 31) * 4 + g) * FSTRIDE;

  int budget = 1 << 22;   // anti-hang

  const int srow = (tid >> 7) * 16 + ((tid >> 4) & 3) * 4;
  const int scol = ((tid >> 6) & 1) * 32 + (tid & 15);

  __syncthreads();

  for (int k = 0; k < NCH; ++k) {
    const int t0 = k * CH;
    if (t0 == 256) load_phase(1);

    // ---- once-per-chunk sync: wave 0 polls (all lanes same addr = 1 request)
    if (wid == 0) {
      if (P < 31 && k >= RC) {
        while (budget > 0) {
          int v = __hip_atomic_load(cnext, __ATOMIC_RELAXED, SCOPE);
          if (v >= k + 1 - RC) break;
          --budget; __builtin_amdgcn_s_sleep(2);
        }
        (void)__hip_atomic_load(cnext, __ATOMIC_ACQUIRE, SCOPE);
      }
      if (P > 0) {
        while (budget > 0) {
          int v = __hip_atomic_load(fin, __ATOMIC_RELAXED, SCOPE);
          if (v >= k + 1) break;
          --budget; __builtin_amdgcn_s_sleep(2);
        }
        (void)__hip_atomic_load(fin, __ATOMIC_ACQUIRE, SCOPE);
      }
    }
    __syncthreads();   // Bc: chunk-k input records visible to all waves

    // ---- prime the whole chunk's record loads (P>0)
    u64 pra[CH], prb[CH];
    if (P > 0) {
#pragma unroll
      for (int j = 0; j < CH; ++j) {
        const u64* rj = recin + (size_t)((t0 + j) & RM) * 512 + tid * 2;
        pra[j] = __hip_atomic_load(rj,     __ATOMIC_RELAXED, SCOPE);
        prb[j] = __hip_atomic_load(rj + 1, __ATOMIC_RELAXED, SCOPE);
      }
    }

#pragma unroll 1
    for (int tt = 0; tt < CH; ++tt) {
      const int t = t0 + tt;

      // ---- stage x_t for layer A -> xstA[t&1]
      if (P > 0) {
        u16* xd = xstA[t & 1];
#pragma unroll
        for (int p = 0; p < 4; ++p) {
          xd[(srow + p) * 72 + scol]      = (u16)(pra[tt] >> (16 * p));
          xd[(srow + p) * 72 + scol + 16] = (u16)(prb[tt] >> (16 * p));
        }
      }

      lds_barrier();   // B1: xstA(t), hbA(t-1), hbB(t-1) visible

      // ---- pair 31: projection of step t-1 (h63_{t-1} in hbB[(t+1)&1])
      if (P == 31 && t >= 257) do_proj(t - 1, hbB[(t + 1) & 1]);

      // ================= layer A =================
      f32x4 acc_rz[4], acc_in[2], acc_hn[2];
#pragma unroll
      for (int q = 0; q < 4; ++q) { float v = brzA[q]; f32x4 tv = {v,v,v,v}; acc_rz[q] = tv; }
#pragma unroll
      for (int q = 0; q < 2; ++q) { float v = binA[q]; f32x4 tv = {v,v,v,v}; acc_in[q] = tv;
                                    float w = bhnA[q]; f32x4 tw = {w,w,w,w}; acc_hn[q] = tw; }
      const u16* hsA = hbA[(t + 1) & 1];
#pragma unroll
      for (int kc = 0; kc < 2; ++kc) {
        short8 hA = *(const short8*)(hsA + (rt*16 + lo)*72 + kc*32 + hi*8);
        acc_rz[0] = __builtin_amdgcn_mfma_f32_16x16x32_bf16(hA, whA[0][kc], acc_rz[0], 0, 0, 0);
        acc_rz[1] = __builtin_amdgcn_mfma_f32_16x16x32_bf16(hA, whA[1][kc], acc_rz[1], 0, 0, 0);
        acc_rz[2] = __builtin_amdgcn_mfma_f32_16x16x32_bf16(hA, whA[2][kc], acc_rz[2], 0, 0, 0);
        acc_rz[3] = __builtin_amdgcn_mfma_f32_16x16x32_bf16(hA, whA[3][kc], acc_rz[3], 0, 0, 0);
        acc_hn[0] = __builtin_amdgcn_mfma_f32_16x16x32_bf16(hA, whA[4][kc], acc_hn[0], 0, 0, 0);
        acc_hn[1] = __builtin_amdgcn_mfma_f32_16x16x32_bf16(hA, whA[5][kc], acc_hn[1], 0, 0, 0);
      }
      short8 xfA[4] = {zf8, zf8, zf8, zf8};
      if (P > 0) {
        const u16* xs = xstA[t & 1];
#pragma unroll
        for (int kc = 0; kc < 2; ++kc)
          xfA[kc] = *(const short8*)(xs + (rt*16 + lo)*72 + kc*32 + hi*8);
      } else {
        int tx = (t < 256) ? t : ((t == 256) ? 0 : t - 257);
#pragma unroll
        for (int kc = 0; kc < 4; ++kc)
          xfA[kc] = ld8(ctx_, (brow * 256 + tx) * 128 + kc*32 + hi*8);
      }
      if (!(P == 0 && t == 256)) {
#pragma unroll
        for (int kc = 0; kc < 4; ++kc) {
          if (kc < NKCA) {
            acc_rz[0] = __builtin_amdgcn_mfma_f32_16x16x32_bf16(xfA[kc], wiA[0][kc], acc_rz[0], 0, 0, 0);
            acc_rz[1] = __builtin_amdgcn_mfma_f32_16x16x32_bf16(xfA[kc], wiA[1][kc], acc_rz[1], 0, 0, 0);
            acc_rz[2] = __builtin_amdgcn_mfma_f32_16x16x32_bf16(xfA[kc], wiA[2][kc], acc_rz[2], 0, 0, 0);
            acc_rz[3] = __builtin_amdgcn_mfma_f32_16x16x32_bf16(xfA[kc], wiA[3][kc], acc_rz[3], 0, 0, 0);
            acc_in[0] = __builtin_amdgcn_mfma_f32_16x16x32_bf16(xfA[kc], wiA[4][kc], acc_in[0], 0, 0, 0);
            acc_in[1] = __builtin_amdgcn_mfma_f32_16x16x32_bf16(xfA[kc], wiA[5][kc], acc_in[1], 0, 0, 0);
          }
        }
      }
      u16 hAb[2][4];
#pragma unroll
      for (int q = 0; q < 2; ++q)
#pragma unroll
        for (int p = 0; p < 4; ++p) {
          float r = sigm(acc_rz[q][p]);
          float z = sigm(acc_rz[2 + q][p]);
          float n = tanhf_(acc_in[q][p] + r * acc_hn[q][p]);
          float h = n + z * (hprevA[q][p] - n);
          h = fminf(1.f, fmaxf(-1.f, h));
          hprevA[q][p] = h;
          hAb[q][p] = f2bf(h);
        }
      {  // h_A -> hbA[t&1] (recurrence) and xstB (x for layer B)
        u16* hd = hbA[t & 1];
#pragma unroll
        for (int q = 0; q < 2; ++q)
#pragma unroll
          for (int p = 0; p < 4; ++p) {
            int ridx = (rt*16 + hi*4 + p) * 72 + cs*32 + q*16 + lo;
            hd[ridx] = hAb[q][p];
            xstB[ridx] = hAb[q][p];
          }
      }

      lds_barrier();   // B2: xstB(t) visible

      // ================= layer B =================
#pragma unroll
      for (int q = 0; q < 4; ++q) { float v = brzB[q]; f32x4 tv = {v,v,v,v}; acc_rz[q] = tv; }
#pragma unroll
      for (int q = 0; q < 2; ++q) { float v = binB[q]; f32x4 tv = {v,v,v,v}; acc_in[q] = tv;
                                    float w = bhnB[q]; f32x4 tw = {w,w,w,w}; acc_hn[q] = tw; }
      const u16* hsB = hbB[(t + 1) & 1];
#pragma unroll
      for (int kc = 0; kc < 2; ++kc) {
        short8 hB = *(const short8*)(hsB + (rt*16 + lo)*72 + kc*32 + hi*8);
        short8 xB = *(const short8*)(xstB + (rt*16 + lo)*72 + kc*32 + hi*8);
        acc_rz[0] = __builtin_amdgcn_mfma_f32_16x16x32_bf16(hB, whB[0][kc], acc_rz[0], 0, 0, 0);
        acc_rz[1] = __builtin_amdgcn_mfma_f32_16x16x32_bf16(hB, whB[1][kc], acc_rz[1], 0, 0, 0);
        acc_rz[2] = __builtin_amdgcn_mfma_f32_16x16x32_bf16(hB, whB[2][kc], acc_rz[2], 0, 0, 0);
        acc_rz[3] = __builtin_amdgcn_mfma_f32_16x16x32_bf16(hB, whB[3][kc], acc_rz[3], 0, 0, 0);
        acc_hn[0] = __builtin_amdgcn_mfma_f32_16x16x32_bf16(hB, whB[4][kc], acc_hn[0], 0, 0, 0);
        acc_hn[1] = __builtin_amdgcn_mfma_f32_16x16x32_bf16(hB, whB[5][kc], acc_hn[1], 0, 0, 0);
        acc_rz[0] = __builtin_amdgcn_mfma_f32_16x16x32_bf16(xB, wiB[0][kc], acc_rz[0], 0, 0, 0);
        acc_rz[1] = __builtin_amdgcn_mfma_f32_16x16x32_bf16(xB, wiB[1][kc], acc_rz[1], 0, 0, 0);
        acc_rz[2] = __builtin_amdgcn_mfma_f32_16x16x32_bf16(xB, wiB[2][kc], acc_rz[2], 0, 0, 0);
        acc_rz[3] = __builtin_amdgcn_mfma_f32_16x16x32_bf16(xB, wiB[3][kc], acc_rz[3], 0, 0, 0);
        acc_in[0] = __builtin_amdgcn_mfma_f32_16x16x32_bf16(xB, wiB[4][kc], acc_in[0], 0, 0, 0);
        acc_in[1] = __builtin_amdgcn_mfma_f32_16x16x32_bf16(xB, wiB[5][kc], acc_in[1], 0, 0, 0);
      }
      u16 hBb[2][4];
#pragma unroll
      for (int q = 0; q < 2; ++q)
#pragma unroll
        for (int p = 0; p < 4; ++p) {
          float r = sigm(acc_rz[q][p]);
          float z = sigm(acc_rz[2 + q][p]);
          float n = tanhf_(acc_in[q][p] + r * acc_hn[q][p]);
          float h = n + z * (hprevB[q][p] - n);
          h = fminf(1.f, fmaxf(-1.f, h));
          hprevB[q][p] = h;
          hBb[q][p] = f2bf(h);
        }
      {
        u16* hd = hbB[t & 1];
#pragma unroll
        for (int q = 0; q < 2; ++q)
#pragma unroll
          for (int p = 0; p < 4; ++p)
            hd[(rt*16 + hi*4 + p) * 72 + cs*32 + q*16 + lo] = hBb[q][p];
      }
      if (P < 31) {   // record h_B for the next pair
        u64 da = (u64)hBb[0][0] | ((u64)hBb[0][1] << 16) | ((u64)hBb[0][2] << 32) | ((u64)hBb[0][3] << 48);
        u64 db = (u64)hBb[1][0] | ((u64)hBb[1][1] << 16) | ((u64)hBb[1][2] << 32) | ((u64)hBb[1][3] << 48);
        u64* ro = recout + (size_t)(t & RM) * 512 + tid * 2;
        __hip_atomic_store(ro,     da, __ATOMIC_RELAXED, SCOPE);
        __hip_atomic_store(ro + 1, db, __ATOMIC_RELAXED, SCOPE);
      }
    }

    // ---- chunk-end: full barrier drains ALL waves' record stores (vmcnt(0)),
    // then a single release flag per edge
    __syncthreads();
    if (tid == 0) {
      if (P < 31) __hip_atomic_store(fout,  k + 1, __ATOMIC_RELEASE, SCOPE);
      if (P > 0)  __hip_atomic_store(cself, k + 1, __ATOMIC_RELEASE, SCOPE);
    }
  }

  // ---- epilogue: projection of the final step (t = 511)
  lds_barrier();
  if (P == 31) do_proj(511, hbB[1]);
}

extern "C" void kernel_launch(void* const* d_in, const int* in_sizes, int n_in,
                              void* d_out, int out_size, void* d_ws, size_t ws_size,
                              hipStream_t stream)
{
  char* ws = (char*)d_ws;
  int* pflag = (int*)ws;                    // per-edge 256B flag lines (124 edges)
  int* cflag = (int*)(ws + 65536);          // per-pair consumer flags (128)
  u64* xbuf  = (u64*)(ws + 262144);         // handoff ring

  size_t avail = (ws_size > 262144) ? ws_size - 262144 : 0;
  size_t per_slot = (size_t)31 * 4 * 4096;  // one ring step across all 31x4 edges
  int R = 1;
  for (int r = 128; r >= 1; r >>= 1)
    if ((size_t)r * per_slot <= avail) { R = r; break; }

  hipMemsetAsync(ws, 0, 262144, stream);    // zero flags every launch

#define LAUNCH(CHV)                                                        \
  gru_pipeline<CHV><<<128, 256, 0, stream>>>(                              \
      d_in[0], d_in[1], d_in[2], d_in[3], d_in[4], d_in[5],                \
      d_in[6], d_in[7], d_in[8], d_in[9], d_in[10], d_in[11], d_in[12],    \
      d_out, pflag, cflag, xbuf, R)

  if      (R >= 8) LAUNCH(4);
  else if (R >= 4) LAUNCH(2);
  else             LAUNCH(1);
#undef LAUNCH
  (void)in_sizes; (void)n_in; (void)out_size;
}